// Round 6
// baseline (151.726 us; speedup 1.0000x reference)
//
#include <hip/hip_runtime.h>
#include <math.h>

typedef __attribute__((ext_vector_type(8))) short short8;
typedef __attribute__((ext_vector_type(4))) float f32x4;
typedef unsigned short ushortT;

#define NB     16
#define CIN    512
#define TT     2048
#define COUT2  1024
#define NSTYLE 128
#define KKTOT  1536      // 3 * 512
#define TPAD   2050      // T + 2 pad rows
#define NT32   48        // K-tiles of 32

#define SCALE_LIN  0.088388347648318447f
#define SCALE_CONV 0.014731391274719736f

__device__ __forceinline__ ushortT f2bf(float f) {
  union { float f; unsigned u; } v; v.f = f;
  unsigned r = v.u + 0x7fffu + ((v.u >> 16) & 1u);
  return (ushortT)(r >> 16);
}

__device__ __forceinline__ void gload16(const void* g, void* l) {
  __builtin_amdgcn_global_load_lds(
      (const __attribute__((address_space(1))) void*)g,
      (__attribute__((address_space(3))) void*)l, 16, 0, 0);
}

// ---------------- s / beta + pad-row zeroing ----------------
__global__ void style_kernel(const float* __restrict__ c_trg,
                             const float* __restrict__ w_s, const float* __restrict__ b_s,
                             const float* __restrict__ w_b, const float* __restrict__ b_b,
                             float* __restrict__ s, float* __restrict__ beta,
                             ushortT* __restrict__ xT) {
  int gid = blockIdx.x * 256 + threadIdx.x;   // 0..8191 = b*512 + ci
  int b = gid >> 9, ci = gid & 511;
  const float* ct = c_trg + b * NSTYLE;
  const float* ws = w_s + ci * NSTYLE;
  const float* wb = w_b + ci * NSTYLE;
  float as = 0.f, ab = 0.f;
#pragma unroll 8
  for (int j = 0; j < NSTYLE; ++j) {
    float c = ct[j];
    as += c * ws[j];
    ab += c * wb[j];
  }
  s[gid]    = as * SCALE_LIN + b_s[ci];
  beta[gid] = ab * SCALE_LIN + b_b[ci];
  xT[(size_t)b * TPAD * CIN + ci] = 0;
  xT[((size_t)b * TPAD + TPAD - 1) * CIN + ci] = 0;
}

// ---------------- x [b][ci][t] f32 -> xT [b][t+1][ci] bf16 ----------------
__global__ void xpose_kernel(const float* __restrict__ x, ushortT* __restrict__ xT) {
  int b = blockIdx.z, ct = blockIdx.y, tt = blockIdx.x;
  int t0 = tt * 64, ci0 = ct * 64;
  __shared__ float tile[64][65];
  const float* xB = x + (size_t)b * CIN * TT;
  int rr = threadIdx.x >> 4;   // 0..15
  int c4 = threadIdx.x & 15;   // 0..15
#pragma unroll
  for (int it = 0; it < 4; ++it) {
    int ci = rr + it * 16;
    float4 v = *(const float4*)(xB + (size_t)(ci0 + ci) * TT + t0 + c4 * 4);
    tile[ci][c4 * 4 + 0] = v.x; tile[ci][c4 * 4 + 1] = v.y;
    tile[ci][c4 * 4 + 2] = v.z; tile[ci][c4 * 4 + 3] = v.w;
  }
  __syncthreads();
  ushortT* xTB = xT + (size_t)b * TPAD * CIN;
#pragma unroll
  for (int it = 0; it < 4; ++it) {
    int t = rr + it * 16;
    ushort4 o;
    o.x = f2bf(tile[c4 * 4 + 0][t]); o.y = f2bf(tile[c4 * 4 + 1][t]);
    o.z = f2bf(tile[c4 * 4 + 2][t]); o.w = f2bf(tile[c4 * 4 + 3][t]);
    *(ushort4*)(xTB + (size_t)(1 + t0 + t) * CIN + ci0 + c4 * 4) = o;
  }
}

// ---------------- modulate + demod-normalize weights -> bf16 ----------------
// One block per co; loops all 16 batches so weight row is read ONCE (was 16x).
__global__ void modw_kernel(const float* __restrict__ weight,
                            const float* __restrict__ s, const float* __restrict__ beta,
                            ushortT* __restrict__ wnorm) {
  int co = blockIdx.x, tid = threadIdx.x;    // 256 threads, 2 ci (6 floats) each
  int ci = tid * 2;
  const float* wp = weight + (size_t)co * KKTOT + (size_t)ci * 3;
  float2 va = *(const float2*)(wp);
  float2 vb = *(const float2*)(wp + 2);
  float2 vc = *(const float2*)(wp + 4);
  float v0 = va.x, v1 = va.y, v2 = vb.x, v3 = vb.y, v4 = vc.x, v5 = vc.y;
  int r = ((co & 511) << 1) | (co >> 9);     // GLU-interleaved row
  __shared__ float rs[4], rq[4];
  for (int b = 0; b < NB; ++b) {
    float2 sv = *(const float2*)(s + b * CIN + ci);
    float2 ev = *(const float2*)(beta + b * CIN + ci);
    float w0 = SCALE_CONV * (v0 * sv.x + ev.x);
    float w1 = SCALE_CONV * (v1 * sv.x + ev.x);
    float w2 = SCALE_CONV * (v2 * sv.x + ev.x);
    float w3 = SCALE_CONV * (v3 * sv.y + ev.y);
    float w4 = SCALE_CONV * (v4 * sv.y + ev.y);
    float w5 = SCALE_CONV * (v5 * sv.y + ev.y);
    float sum = w0 + w1 + w2 + w3 + w4 + w5;
    float sq  = w0*w0 + w1*w1 + w2*w2 + w3*w3 + w4*w4 + w5*w5;
#pragma unroll
    for (int off = 32; off; off >>= 1) {
      sum += __shfl_xor(sum, off);
      sq  += __shfl_xor(sq,  off);
    }
    if ((tid & 63) == 0) { rs[tid >> 6] = sum; rq[tid >> 6] = sq; }
    __syncthreads();
    float mean  = (rs[0] + rs[1] + rs[2] + rs[3]) * (1.0f / 1536.0f);
    float demod = rsqrtf(rq[0] + rq[1] + rq[2] + rq[3] + 1e-8f);
    ushortT* dst = wnorm + ((size_t)b * COUT2 + r) * KKTOT;
    ushort2 p0, p1, p2;
    p0.x = f2bf((w0 - mean) * demod); p0.y = f2bf((w3 - mean) * demod);
    p1.x = f2bf((w1 - mean) * demod); p1.y = f2bf((w4 - mean) * demod);
    p2.x = f2bf((w2 - mean) * demod); p2.y = f2bf((w5 - mean) * demod);
    *(ushort2*)(dst +        ci) = p0;
    *(ushort2*)(dst +  512 + ci) = p1;
    *(ushort2*)(dst + 1024 + ci) = p2;
    __syncthreads();   // WAR on rs/rq before next b
  }
}

// ---------------- main conv-as-GEMM: 256x128 tile, BK=32, 48KB LDS, 2 wg/CU ----
// Per dbuf d: A region [256 rows][32 cols] bf16 (16KB) at elem d*12288,
//             B region [128 rows][32 cols] bf16 (8KB)  at elem d*12288+8192.
// Rows 64B = 4x16B blocks, XOR-swizzled by (row>>1)&3 (proven 0-conflict pattern).

#define AFRAG(d, f) (*(const short8*)(ldsc + (d) * 24576 + aoff + (f) * 1024))
#define BFRAG(d, g) (*(const short8*)(ldsc + (d) * 24576 + 16384 + boff + (g) * 1024))

#define STAGE(dn, kt) do { int kc_ = (kt) * 32;                                 \
    gload16(sA0 + kc_, ldsw + (dn) * 12288 + dst8);                             \
    gload16(sA1 + kc_, ldsw + (dn) * 12288 + 4096 + dst8);                      \
    gload16(sB0 + kc_, ldsw + (dn) * 12288 + 8192 + dst8);                      \
  } while (0)

// One K-tile: read 8 frags from buf dc, stage tile ktn into buf dc^1,
// 16 MFMA, vmcnt(0) (staged data landed), one barrier.
#define TILE(dc, ktn, DO_STAGE) do {                                            \
    short8 af0 = AFRAG(dc, 0), af1 = AFRAG(dc, 1);                              \
    short8 af2 = AFRAG(dc, 2), af3 = AFRAG(dc, 3);                              \
    short8 bf0 = BFRAG(dc, 0), bf1 = BFRAG(dc, 1);                              \
    short8 bf2 = BFRAG(dc, 2), bf3 = BFRAG(dc, 3);                              \
    if (DO_STAGE) STAGE((dc) ^ 1, ktn);                                         \
    __builtin_amdgcn_s_setprio(1);                                              \
    acc[0][0] = __builtin_amdgcn_mfma_f32_16x16x32_bf16(af0, bf0, acc[0][0], 0, 0, 0); \
    acc[0][1] = __builtin_amdgcn_mfma_f32_16x16x32_bf16(af0, bf1, acc[0][1], 0, 0, 0); \
    acc[0][2] = __builtin_amdgcn_mfma_f32_16x16x32_bf16(af0, bf2, acc[0][2], 0, 0, 0); \
    acc[0][3] = __builtin_amdgcn_mfma_f32_16x16x32_bf16(af0, bf3, acc[0][3], 0, 0, 0); \
    acc[1][0] = __builtin_amdgcn_mfma_f32_16x16x32_bf16(af1, bf0, acc[1][0], 0, 0, 0); \
    acc[1][1] = __builtin_amdgcn_mfma_f32_16x16x32_bf16(af1, bf1, acc[1][1], 0, 0, 0); \
    acc[1][2] = __builtin_amdgcn_mfma_f32_16x16x32_bf16(af1, bf2, acc[1][2], 0, 0, 0); \
    acc[1][3] = __builtin_amdgcn_mfma_f32_16x16x32_bf16(af1, bf3, acc[1][3], 0, 0, 0); \
    acc[2][0] = __builtin_amdgcn_mfma_f32_16x16x32_bf16(af2, bf0, acc[2][0], 0, 0, 0); \
    acc[2][1] = __builtin_amdgcn_mfma_f32_16x16x32_bf16(af2, bf1, acc[2][1], 0, 0, 0); \
    acc[2][2] = __builtin_amdgcn_mfma_f32_16x16x32_bf16(af2, bf2, acc[2][2], 0, 0, 0); \
    acc[2][3] = __builtin_amdgcn_mfma_f32_16x16x32_bf16(af2, bf3, acc[2][3], 0, 0, 0); \
    acc[3][0] = __builtin_amdgcn_mfma_f32_16x16x32_bf16(af3, bf0, acc[3][0], 0, 0, 0); \
    acc[3][1] = __builtin_amdgcn_mfma_f32_16x16x32_bf16(af3, bf1, acc[3][1], 0, 0, 0); \
    acc[3][2] = __builtin_amdgcn_mfma_f32_16x16x32_bf16(af3, bf2, acc[3][2], 0, 0, 0); \
    acc[3][3] = __builtin_amdgcn_mfma_f32_16x16x32_bf16(af3, bf3, acc[3][3], 0, 0, 0); \
    __builtin_amdgcn_s_setprio(0);                                              \
    __builtin_amdgcn_sched_barrier(0);                                          \
    asm volatile("s_waitcnt vmcnt(0)" ::: "memory");                            \
    __builtin_amdgcn_sched_barrier(0);                                          \
    __builtin_amdgcn_s_barrier();                                               \
    __builtin_amdgcn_sched_barrier(0);                                          \
  } while (0)

__global__ __launch_bounds__(512, 4)
void conv_gemm(const ushortT* __restrict__ wnorm, const ushortT* __restrict__ xT,
               float* __restrict__ out) {
  extern __shared__ ushortT ldsw[];
  const char* ldsc = (const char*)ldsw;

  // XCD-chunked bijective swizzle (1024 blocks % 8 == 0)
  int orig = blockIdx.x;
  int wgid = (orig & 7) * 128 + (orig >> 3);
  int b  = wgid >> 6;
  int mt = (wgid >> 4) & 3;
  int nt = wgid & 15;
  int co0 = mt * 256, t0 = nt * 128;

  int tid = threadIdx.x;
  int l = tid & 63, w = tid >> 6;
  int wm = w >> 1, wn = w & 1;           // 4M x 2N wave grid

  // staging constants (proven): row r0 = tid>>2, swizzled 16B-block offset
  int r0 = tid >> 2;
  int jbs8 = (((tid & 3) ^ ((r0 >> 1) & 3)) << 3);
  int dst8 = tid * 8;
  // ds_read constants (proven 0-conflict 16x16 pattern)
  int cb = ((l >> 4) ^ ((l >> 1) & 3));
  int aoff = (wm * 64 + (l & 15)) * 64 + cb * 16;
  int boff = (wn * 64 + (l & 15)) * 64 + cb * 16;

  const ushortT* wB = wnorm + (size_t)b * COUT2 * KKTOT;
  const ushortT* xB = xT + (size_t)b * TPAD * CIN;
  const ushortT* sA0 = wB + (size_t)(co0 + r0) * KKTOT + jbs8;
  const ushortT* sA1 = sA0 + (size_t)128 * KKTOT;
  // tap*CIN + ci == flat kk (CIN==512): B staging is a flat kc offset
  const ushortT* sB0 = xB + (size_t)(t0 + r0) * CIN + jbs8;

  f32x4 acc[4][4];
#pragma unroll
  for (int i = 0; i < 4; ++i)
#pragma unroll
    for (int j = 0; j < 4; ++j)
      acc[i][j] = (f32x4){0.f, 0.f, 0.f, 0.f};

  // prologue: stage tile 0 into buf0
  STAGE(0, 0);
  asm volatile("s_waitcnt vmcnt(0)" ::: "memory");
  __builtin_amdgcn_sched_barrier(0);
  __builtin_amdgcn_s_barrier();
  __builtin_amdgcn_sched_barrier(0);

  for (int j = 0; j < 23; ++j) {       // tiles 0..45
    TILE(0, 2 * j + 1, 1);
    TILE(1, 2 * j + 2, 1);
  }
  TILE(0, 47, 1);                      // tile 46, stage 47
  TILE(1, 0, 0);                       // tile 47, no stage

  // epilogue: GLU-interleaved co' rows; (x,y)/(z,w) = (a,g) channel pairs
#pragma unroll
  for (int mi = 0; mi < 4; ++mi) {
    int cop = co0 + wm * 64 + mi * 16 + ((l >> 4) << 2);
    int c = cop >> 1;
    size_t obase = ((size_t)b * (COUT2 / 2) + c) * TT;
#pragma unroll
    for (int ni = 0; ni < 4; ++ni) {
      int t = t0 + wn * 64 + ni * 16 + (l & 15);
      f32x4 v = acc[mi][ni];
      out[obase + t]      = v.x / (1.f + __expf(-v.y));
      out[obase + TT + t] = v.z / (1.f + __expf(-v.w));
    }
  }
}

extern "C" void kernel_launch(void* const* d_in, const int* in_sizes, int n_in,
                              void* d_out, int out_size, void* d_ws, size_t ws_size,
                              hipStream_t stream) {
  const float* x      = (const float*)d_in[0];
  const float* c_trg  = (const float*)d_in[2];
  const float* w_s    = (const float*)d_in[3];
  const float* b_s    = (const float*)d_in[4];
  const float* w_b    = (const float*)d_in[5];
  const float* b_b    = (const float*)d_in[6];
  const float* weight = (const float*)d_in[7];
  float* out = (float*)d_out;

  char* ws = (char*)d_ws;
  float*   s     = (float*)ws;                           // 32 KB
  float*   beta  = (float*)(ws + 32768);                 // 32 KB
  ushortT* xT    = (ushortT*)(ws + 65536);               // 33,587,200 B
  ushortT* wnorm = (ushortT*)(ws + 65536 + 33587200);    // 50,331,648 B

  hipFuncSetAttribute((const void*)conv_gemm,
                      hipFuncAttributeMaxDynamicSharedMemorySize, 49152);

  style_kernel<<<32, 256, 0, stream>>>(c_trg, w_s, b_s, w_b, b_b, s, beta, xT);
  xpose_kernel<<<dim3(32, 8, 16), 256, 0, stream>>>(x, xT);
  modw_kernel<<<1024, 256, 0, stream>>>(weight, s, beta, wnorm);
  conv_gemm<<<1024, 512, 49152, stream>>>(wnorm, xT, out);
}

// Round 7
// 147.718 us; speedup vs baseline: 1.0271x; 1.0271x over previous
//
#include <hip/hip_runtime.h>
#include <math.h>

typedef __attribute__((ext_vector_type(8))) short short8;
typedef __attribute__((ext_vector_type(4))) float f32x4;
typedef unsigned short ushortT;

#define NB     16
#define CIN    512
#define TT     2048
#define COUT2  1024
#define NSTYLE 128
#define KKTOT  1536      // 3 * 512
#define TPAD   2050      // T + 2 pad rows

#define SCALE_LIN  0.088388347648318447f
#define SCALE_CONV 0.014731391274719736f

__device__ __forceinline__ ushortT f2bf(float f) {
  union { float f; unsigned u; } v; v.f = f;
  unsigned r = v.u + 0x7fffu + ((v.u >> 16) & 1u);
  return (ushortT)(r >> 16);
}

__device__ __forceinline__ void gload16(const void* g, void* l) {
  __builtin_amdgcn_global_load_lds(
      (const __attribute__((address_space(1))) void*)g,
      (__attribute__((address_space(3))) void*)l, 16, 0, 0);
}

// ---------------- s / beta + pad-row zeroing ----------------
__global__ void style_kernel(const float* __restrict__ c_trg,
                             const float* __restrict__ w_s, const float* __restrict__ b_s,
                             const float* __restrict__ w_b, const float* __restrict__ b_b,
                             float* __restrict__ s, float* __restrict__ beta,
                             ushortT* __restrict__ xT) {
  int gid = blockIdx.x * 256 + threadIdx.x;   // 0..8191 = b*512 + ci
  int b = gid >> 9, ci = gid & 511;
  const float* ct = c_trg + b * NSTYLE;
  const float* ws = w_s + ci * NSTYLE;
  const float* wb = w_b + ci * NSTYLE;
  float as = 0.f, ab = 0.f;
#pragma unroll 8
  for (int j = 0; j < NSTYLE; ++j) {
    float c = ct[j];
    as += c * ws[j];
    ab += c * wb[j];
  }
  s[gid]    = as * SCALE_LIN + b_s[ci];
  beta[gid] = ab * SCALE_LIN + b_b[ci];
  xT[(size_t)b * TPAD * CIN + ci] = 0;
  xT[((size_t)b * TPAD + TPAD - 1) * CIN + ci] = 0;
}

// ---------------- x [b][ci][t] f32 -> xT [b][t+1][ci] bf16 ----------------
__global__ void xpose_kernel(const float* __restrict__ x, ushortT* __restrict__ xT) {
  int b = blockIdx.z, ct = blockIdx.y, tt = blockIdx.x;
  int t0 = tt * 64, ci0 = ct * 64;
  __shared__ float tile[64][65];
  const float* xB = x + (size_t)b * CIN * TT;
  int rr = threadIdx.x >> 4;   // 0..15
  int c4 = threadIdx.x & 15;   // 0..15
#pragma unroll
  for (int it = 0; it < 4; ++it) {
    int ci = rr + it * 16;
    float4 v = *(const float4*)(xB + (size_t)(ci0 + ci) * TT + t0 + c4 * 4);
    tile[ci][c4 * 4 + 0] = v.x; tile[ci][c4 * 4 + 1] = v.y;
    tile[ci][c4 * 4 + 2] = v.z; tile[ci][c4 * 4 + 3] = v.w;
  }
  __syncthreads();
  ushortT* xTB = xT + (size_t)b * TPAD * CIN;
#pragma unroll
  for (int it = 0; it < 4; ++it) {
    int t = rr + it * 16;
    ushort4 o;
    o.x = f2bf(tile[c4 * 4 + 0][t]); o.y = f2bf(tile[c4 * 4 + 1][t]);
    o.z = f2bf(tile[c4 * 4 + 2][t]); o.w = f2bf(tile[c4 * 4 + 3][t]);
    *(ushort4*)(xTB + (size_t)(1 + t0 + t) * CIN + ci0 + c4 * 4) = o;
  }
}

// ---------------- modulate + demod-normalize weights -> bf16 ----------------
// One block per co; loops all 16 batches so weight row is read ONCE.
__global__ void modw_kernel(const float* __restrict__ weight,
                            const float* __restrict__ s, const float* __restrict__ beta,
                            ushortT* __restrict__ wnorm) {
  int co = blockIdx.x, tid = threadIdx.x;    // 256 threads, 2 ci (6 floats) each
  int ci = tid * 2;
  const float* wp = weight + (size_t)co * KKTOT + (size_t)ci * 3;
  float2 va = *(const float2*)(wp);
  float2 vb = *(const float2*)(wp + 2);
  float2 vc = *(const float2*)(wp + 4);
  float v0 = va.x, v1 = va.y, v2 = vb.x, v3 = vb.y, v4 = vc.x, v5 = vc.y;
  int r = ((co & 511) << 1) | (co >> 9);     // GLU-interleaved row
  __shared__ float rs[4], rq[4];
  for (int b = 0; b < NB; ++b) {
    float2 sv = *(const float2*)(s + b * CIN + ci);
    float2 ev = *(const float2*)(beta + b * CIN + ci);
    float w0 = SCALE_CONV * (v0 * sv.x + ev.x);
    float w1 = SCALE_CONV * (v1 * sv.x + ev.x);
    float w2 = SCALE_CONV * (v2 * sv.x + ev.x);
    float w3 = SCALE_CONV * (v3 * sv.y + ev.y);
    float w4 = SCALE_CONV * (v4 * sv.y + ev.y);
    float w5 = SCALE_CONV * (v5 * sv.y + ev.y);
    float sum = w0 + w1 + w2 + w3 + w4 + w5;
    float sq  = w0*w0 + w1*w1 + w2*w2 + w3*w3 + w4*w4 + w5*w5;
#pragma unroll
    for (int off = 32; off; off >>= 1) {
      sum += __shfl_xor(sum, off);
      sq  += __shfl_xor(sq,  off);
    }
    if ((tid & 63) == 0) { rs[tid >> 6] = sum; rq[tid >> 6] = sq; }
    __syncthreads();
    float mean  = (rs[0] + rs[1] + rs[2] + rs[3]) * (1.0f / 1536.0f);
    float demod = rsqrtf(rq[0] + rq[1] + rq[2] + rq[3] + 1e-8f);
    ushortT* dst = wnorm + ((size_t)b * COUT2 + r) * KKTOT;
    ushort2 p0, p1, p2;
    p0.x = f2bf((w0 - mean) * demod); p0.y = f2bf((w3 - mean) * demod);
    p1.x = f2bf((w1 - mean) * demod); p1.y = f2bf((w4 - mean) * demod);
    p2.x = f2bf((w2 - mean) * demod); p2.y = f2bf((w5 - mean) * demod);
    *(ushort2*)(dst +        ci) = p0;
    *(ushort2*)(dst +  512 + ci) = p1;
    *(ushort2*)(dst + 1024 + ci) = p2;
    __syncthreads();   // WAR on rs/rq before next b
  }
}

// ---------------- main conv-as-GEMM: 256x256 tile, 4 waves, 128x128/wave ------
// LDS: buf d -> A region [256][32] bf16 @ byte d*32768, B region @ d*32768+16384.
// Rows 64B = 4x16B blocks XOR-swizzled by (row>>1)&3 (proven 0-conflict).
// 1 wave/SIMD; in-wave pipeline: reads(k+1) + stage(k+2) issued before MFMA(k).

#define AFRAG(d, f) (*(const short8*)(ldsc + (d) * 32768 + aoff + (f) * 1024))
#define BFRAG(d, g) (*(const short8*)(ldsc + (d) * 32768 + 16384 + boff + (g) * 1024))

#define STAGE(dn, kt) do { int kc_ = (kt) * 32;                                  \
    gload16(sA0 + kc_,                ldsw + (dn) * 16384 + dst8);               \
    gload16(sA0 + kc_ +  64 * KKTOT,  ldsw + (dn) * 16384 + 2048 + dst8);        \
    gload16(sA0 + kc_ + 128 * KKTOT,  ldsw + (dn) * 16384 + 4096 + dst8);        \
    gload16(sA0 + kc_ + 192 * KKTOT,  ldsw + (dn) * 16384 + 6144 + dst8);        \
    gload16(sB0 + kc_,                ldsw + (dn) * 16384 + 8192 + dst8);        \
    gload16(sB0 + kc_ +  64 * CIN,    ldsw + (dn) * 16384 + 10240 + dst8);       \
    gload16(sB0 + kc_ + 128 * CIN,    ldsw + (dn) * 16384 + 12288 + dst8);       \
    gload16(sB0 + kc_ + 192 * CIN,    ldsw + (dn) * 16384 + 14336 + dst8);       \
  } while (0)

// ITER k: [vmcnt(0); barrier][16 ds_reads k+1 -> NXT][stage k+2][64 MFMA on CUR][lgkm(0)]
#define ITER(CA, CB, NA, NB_, RB, SB, KT, DOSTAGE, DOREAD) do {                  \
    asm volatile("s_waitcnt vmcnt(0)" ::: "memory");                             \
    __builtin_amdgcn_sched_barrier(0);                                           \
    __builtin_amdgcn_s_barrier();                                                \
    __builtin_amdgcn_sched_barrier(0);                                           \
    if (DOREAD) {                                                                \
      _Pragma("unroll") for (int f_ = 0; f_ < 8; ++f_) NA[f_]  = AFRAG(RB, f_);  \
      _Pragma("unroll") for (int g_ = 0; g_ < 8; ++g_) NB_[g_] = BFRAG(RB, g_);  \
    }                                                                            \
    if (DOSTAGE) STAGE(SB, KT);                                                  \
    __builtin_amdgcn_s_setprio(1);                                               \
    _Pragma("unroll") for (int f_ = 0; f_ < 8; ++f_)                             \
      _Pragma("unroll") for (int g_ = 0; g_ < 8; ++g_)                           \
        acc[f_][g_] = __builtin_amdgcn_mfma_f32_16x16x32_bf16(                   \
            CA[f_], CB[g_], acc[f_][g_], 0, 0, 0);                               \
    __builtin_amdgcn_s_setprio(0);                                               \
    __builtin_amdgcn_sched_barrier(0);                                           \
    asm volatile("s_waitcnt lgkmcnt(0)" ::: "memory");                           \
    __builtin_amdgcn_sched_barrier(0);                                           \
  } while (0)

__global__ __launch_bounds__(256, 1)
void conv_gemm(const ushortT* __restrict__ wnorm, const ushortT* __restrict__ xT,
               float* __restrict__ out) {
  extern __shared__ ushortT ldsw[];
  const char* ldsc = (const char*)ldsw;

  // XCD-chunked bijective swizzle (512 blocks % 8 == 0)
  int orig = blockIdx.x;
  int wgid = (orig & 7) * 64 + (orig >> 3);
  int b  = wgid >> 5;
  int i5 = wgid & 31;
  int mt = i5 >> 3, nt = i5 & 7;
  int co0 = mt * 256, t0 = nt * 256;

  int tid = threadIdx.x;
  int l = tid & 63, w = tid >> 6;
  int wm = w >> 1, wn = w & 1;           // 2M x 2N wave grid, 128x128 per wave

  // staging constants: r0 = row of gload q=0 (0..63), swizzled 16B-block offset
  int r0 = tid >> 2;
  int jbs8 = (((tid & 3) ^ ((r0 >> 1) & 3)) << 3);
  int dst8 = tid * 8;
  // ds_read constants (proven 0-conflict 16x16 pattern; holds for all f since 16|f*16)
  int cb = ((l >> 4) ^ ((l >> 1) & 3));
  int aoff = (wm * 128 + (l & 15)) * 64 + cb * 16;
  int boff = (wn * 128 + (l & 15)) * 64 + cb * 16;

  const ushortT* wB = wnorm + (size_t)b * COUT2 * KKTOT;
  const ushortT* xB = xT + (size_t)b * TPAD * CIN;
  const ushortT* sA0 = wB + (size_t)(co0 + r0) * KKTOT + jbs8;
  // tap*CIN + ci == flat kk (CIN==512): B staging is a flat kc offset
  const ushortT* sB0 = xB + (size_t)(t0 + r0) * CIN + jbs8;

  f32x4 acc[8][8];
#pragma unroll
  for (int i = 0; i < 8; ++i)
#pragma unroll
    for (int j = 0; j < 8; ++j)
      acc[i][j] = (f32x4){0.f, 0.f, 0.f, 0.f};
  short8 Xa[8], Xb[8], Ya[8], Yb[8];

  // prologue: stage tiles 0,1; read frags(0) into X
  STAGE(0, 0); STAGE(1, 1);
  asm volatile("s_waitcnt vmcnt(8)" ::: "memory");   // tile-0's 8 loads landed
  __builtin_amdgcn_sched_barrier(0);
  __builtin_amdgcn_s_barrier();
  __builtin_amdgcn_sched_barrier(0);
#pragma unroll
  for (int f = 0; f < 8; ++f) Xa[f] = AFRAG(0, f);
#pragma unroll
  for (int g = 0; g < 8; ++g) Xb[g] = BFRAG(0, g);
  asm volatile("s_waitcnt lgkmcnt(0)" ::: "memory");
  __builtin_amdgcn_sched_barrier(0);

  // main loop: k = 0..45 (23 double-iters)
  for (int k2 = 0; k2 < 23; ++k2) {
    ITER(Xa, Xb, Ya, Yb, 1, 0, 2 * k2 + 2, 1, 1);    // k even: stage k+2 -> buf0
    ITER(Ya, Yb, Xa, Xb, 0, 1, 2 * k2 + 3, 1, 1);    // k odd : stage k+2 -> buf1
  }
  // peel k=46 (reads 47, no stage), k=47 (no reads, no stage)
  ITER(Xa, Xb, Ya, Yb, 1, 0, 0, 0, 1);
  ITER(Ya, Yb, Xa, Xb, 0, 0, 0, 0, 0);

  // epilogue: GLU-interleaved co' rows; (x,y)/(z,w) = (a,g) channel pairs
#pragma unroll
  for (int f = 0; f < 8; ++f) {
    int cop = co0 + wm * 128 + f * 16 + ((l >> 4) << 2);
    int c = cop >> 1;
    size_t obase = ((size_t)b * (COUT2 / 2) + c) * TT;
#pragma unroll
    for (int g = 0; g < 8; ++g) {
      int t = t0 + wn * 128 + g * 16 + (l & 15);
      f32x4 v = acc[f][g];
      out[obase + t]      = v.x / (1.f + __expf(-v.y));
      out[obase + TT + t] = v.z / (1.f + __expf(-v.w));
    }
  }
}

extern "C" void kernel_launch(void* const* d_in, const int* in_sizes, int n_in,
                              void* d_out, int out_size, void* d_ws, size_t ws_size,
                              hipStream_t stream) {
  const float* x      = (const float*)d_in[0];
  const float* c_trg  = (const float*)d_in[2];
  const float* w_s    = (const float*)d_in[3];
  const float* b_s    = (const float*)d_in[4];
  const float* w_b    = (const float*)d_in[5];
  const float* b_b    = (const float*)d_in[6];
  const float* weight = (const float*)d_in[7];
  float* out = (float*)d_out;

  char* ws = (char*)d_ws;
  float*   s     = (float*)ws;                           // 32 KB
  float*   beta  = (float*)(ws + 32768);                 // 32 KB
  ushortT* xT    = (ushortT*)(ws + 65536);               // 33,587,200 B
  ushortT* wnorm = (ushortT*)(ws + 65536 + 33587200);    // 50,331,648 B

  hipFuncSetAttribute((const void*)conv_gemm,
                      hipFuncAttributeMaxDynamicSharedMemorySize, 65536);

  style_kernel<<<32, 256, 0, stream>>>(c_trg, w_s, b_s, w_b, b_b, s, beta, xT);
  xpose_kernel<<<dim3(32, 8, 16), 256, 0, stream>>>(x, xT);
  modw_kernel<<<1024, 256, 0, stream>>>(weight, s, beta, wnorm);
  conv_gemm<<<512, 256, 65536, stream>>>(wnorm, xT, out);
}

// Round 8
// 139.998 us; speedup vs baseline: 1.0838x; 1.0551x over previous
//
#include <hip/hip_runtime.h>
#include <math.h>

typedef __attribute__((ext_vector_type(8))) short short8;
typedef __attribute__((ext_vector_type(4))) float f32x4;
typedef unsigned short ushortT;

#define NB     16
#define CIN    512
#define TT     2048
#define COUT2  1024
#define NSTYLE 128
#define KKTOT  1536      // 3 * 512
#define TPAD   2050      // T + 2 pad rows
#define NKT    24        // K-tiles of 64

#define SCALE_LIN  0.088388347648318447f
#define SCALE_CONV 0.014731391274719736f

__device__ __forceinline__ ushortT f2bf(float f) {
  union { float f; unsigned u; } v; v.f = f;
  unsigned r = v.u + 0x7fffu + ((v.u >> 16) & 1u);
  return (ushortT)(r >> 16);
}

__device__ __forceinline__ void gload16(const void* g, void* l) {
  __builtin_amdgcn_global_load_lds(
      (const __attribute__((address_space(1))) void*)g,
      (__attribute__((address_space(3))) void*)l, 16, 0, 0);
}

// ---------------- s / beta + pad-row zeroing ----------------
__global__ void style_kernel(const float* __restrict__ c_trg,
                             const float* __restrict__ w_s, const float* __restrict__ b_s,
                             const float* __restrict__ w_b, const float* __restrict__ b_b,
                             float* __restrict__ s, float* __restrict__ beta,
                             ushortT* __restrict__ xT) {
  int gid = blockIdx.x * 256 + threadIdx.x;   // 0..8191 = b*512 + ci
  int b = gid >> 9, ci = gid & 511;
  const float* ct = c_trg + b * NSTYLE;
  const float* ws = w_s + ci * NSTYLE;
  const float* wb = w_b + ci * NSTYLE;
  float as = 0.f, ab = 0.f;
#pragma unroll 8
  for (int j = 0; j < NSTYLE; ++j) {
    float c = ct[j];
    as += c * ws[j];
    ab += c * wb[j];
  }
  s[gid]    = as * SCALE_LIN + b_s[ci];
  beta[gid] = ab * SCALE_LIN + b_b[ci];
  xT[(size_t)b * TPAD * CIN + ci] = 0;
  xT[((size_t)b * TPAD + TPAD - 1) * CIN + ci] = 0;
}

// ---------------- x [b][ci][t] f32 -> xT [b][t+1][ci] bf16 ----------------
__global__ void xpose_kernel(const float* __restrict__ x, ushortT* __restrict__ xT) {
  int b = blockIdx.z, ct = blockIdx.y, tt = blockIdx.x;
  int t0 = tt * 64, ci0 = ct * 64;
  __shared__ float tile[64][65];
  const float* xB = x + (size_t)b * CIN * TT;
  int rr = threadIdx.x >> 4;   // 0..15
  int c4 = threadIdx.x & 15;   // 0..15
#pragma unroll
  for (int it = 0; it < 4; ++it) {
    int ci = rr + it * 16;
    float4 v = *(const float4*)(xB + (size_t)(ci0 + ci) * TT + t0 + c4 * 4);
    tile[ci][c4 * 4 + 0] = v.x; tile[ci][c4 * 4 + 1] = v.y;
    tile[ci][c4 * 4 + 2] = v.z; tile[ci][c4 * 4 + 3] = v.w;
  }
  __syncthreads();
  ushortT* xTB = xT + (size_t)b * TPAD * CIN;
#pragma unroll
  for (int it = 0; it < 4; ++it) {
    int t = rr + it * 16;
    ushort4 o;
    o.x = f2bf(tile[c4 * 4 + 0][t]); o.y = f2bf(tile[c4 * 4 + 1][t]);
    o.z = f2bf(tile[c4 * 4 + 2][t]); o.w = f2bf(tile[c4 * 4 + 3][t]);
    *(ushort4*)(xTB + (size_t)(1 + t0 + t) * CIN + ci0 + c4 * 4) = o;
  }
}

// ---------------- modulate + demod-normalize weights -> bf16 ----------------
// One block per co; loops all 16 batches so weight row is read ONCE.
__global__ void modw_kernel(const float* __restrict__ weight,
                            const float* __restrict__ s, const float* __restrict__ beta,
                            ushortT* __restrict__ wnorm) {
  int co = blockIdx.x, tid = threadIdx.x;    // 256 threads, 2 ci (6 floats) each
  int ci = tid * 2;
  const float* wp = weight + (size_t)co * KKTOT + (size_t)ci * 3;
  float2 va = *(const float2*)(wp);
  float2 vb = *(const float2*)(wp + 2);
  float2 vc = *(const float2*)(wp + 4);
  float v0 = va.x, v1 = va.y, v2 = vb.x, v3 = vb.y, v4 = vc.x, v5 = vc.y;
  int r = ((co & 511) << 1) | (co >> 9);     // GLU-interleaved row
  __shared__ float rs[4], rq[4];
  for (int b = 0; b < NB; ++b) {
    float2 sv = *(const float2*)(s + b * CIN + ci);
    float2 ev = *(const float2*)(beta + b * CIN + ci);
    float w0 = SCALE_CONV * (v0 * sv.x + ev.x);
    float w1 = SCALE_CONV * (v1 * sv.x + ev.x);
    float w2 = SCALE_CONV * (v2 * sv.x + ev.x);
    float w3 = SCALE_CONV * (v3 * sv.y + ev.y);
    float w4 = SCALE_CONV * (v4 * sv.y + ev.y);
    float w5 = SCALE_CONV * (v5 * sv.y + ev.y);
    float sum = w0 + w1 + w2 + w3 + w4 + w5;
    float sq  = w0*w0 + w1*w1 + w2*w2 + w3*w3 + w4*w4 + w5*w5;
#pragma unroll
    for (int off = 32; off; off >>= 1) {
      sum += __shfl_xor(sum, off);
      sq  += __shfl_xor(sq,  off);
    }
    if ((tid & 63) == 0) { rs[tid >> 6] = sum; rq[tid >> 6] = sq; }
    __syncthreads();
    float mean  = (rs[0] + rs[1] + rs[2] + rs[3]) * (1.0f / 1536.0f);
    float demod = rsqrtf(rq[0] + rq[1] + rq[2] + rq[3] + 1e-8f);
    ushortT* dst = wnorm + ((size_t)b * COUT2 + r) * KKTOT;
    ushort2 p0, p1, p2;
    p0.x = f2bf((w0 - mean) * demod); p0.y = f2bf((w3 - mean) * demod);
    p1.x = f2bf((w1 - mean) * demod); p1.y = f2bf((w4 - mean) * demod);
    p2.x = f2bf((w2 - mean) * demod); p2.y = f2bf((w5 - mean) * demod);
    *(ushort2*)(dst +        ci) = p0;
    *(ushort2*)(dst +  512 + ci) = p1;
    *(ushort2*)(dst + 1024 + ci) = p2;
    __syncthreads();   // WAR on rs/rq before next b
  }
}

// ---------------- main conv-as-GEMM: 256^2 tile, 8-phase pipeline ----------------
// EXACT R3 structure; single change: NO sched_barrier(0) order-pins (m141/m201).
// LDS regions: ridx = ((dbuf*2 + op)*2 + ks), region = [256 rows][32 cols] bf16
// = 16384 bytes. Rows 64B = 4x16B blocks XOR-swizzled by (row>>1)&3. 8 regions = 128 KiB.

#define AFRAG(d, s, f) (*(const short8*)(ldsc + ((d) * 4 + (s)) * 16384 + aoff + (f) * 1024))
#define BFRAG(d, s, g) (*(const short8*)(ldsc + ((d) * 4 + 2 + (s)) * 16384 + boff + (g) * 1024))

#define STAGE_A(d, s, kt) do {                                                   \
    int kc_ = (kt) * 64 + (s) * 32;                                              \
    gload16(wB + (size_t)(co0 + r0) * KKTOT + kc_ + jbs8,                        \
            ldsw + ((d) * 4 + (s)) * 8192 + tid * 8);                            \
    gload16(wB + (size_t)(co0 + r0 + 128) * KKTOT + kc_ + jbs8,                  \
            ldsw + ((d) * 4 + (s)) * 8192 + 4096 + tid * 8);                     \
  } while (0)

#define STAGE_B(d, s, kt) do {                                                   \
    int kc_ = (kt) * 64 + (s) * 32;                                              \
    int tap_ = kc_ >> 9; int ci_ = kc_ & 511;                                    \
    gload16(xB + (size_t)(t0 + r0 + tap_) * CIN + ci_ + jbs8,                    \
            ldsw + ((d) * 4 + 2 + (s)) * 8192 + tid * 8);                        \
    gload16(xB + (size_t)(t0 + r0 + 128 + tap_) * CIN + ci_ + jbs8,              \
            ldsw + ((d) * 4 + 2 + (s)) * 8192 + 4096 + tid * 8);                 \
  } while (0)

// VMN: 6 -> vmcnt(6), 0 -> vmcnt(0), -1 -> none
#define PHASE(d, s, mh, STAGES, VMN) do {                                        \
    short8 a0 = AFRAG(d, s, (mh) * 4 + 0);                                       \
    short8 a1 = AFRAG(d, s, (mh) * 4 + 1);                                       \
    short8 a2 = AFRAG(d, s, (mh) * 4 + 2);                                       \
    short8 a3 = AFRAG(d, s, (mh) * 4 + 3);                                       \
    if ((mh) == 0) {                                                             \
      bf0 = BFRAG(d, s, 0); bf1 = BFRAG(d, s, 1);                                \
      bf2 = BFRAG(d, s, 2); bf3 = BFRAG(d, s, 3);                                \
    }                                                                            \
    STAGES;                                                                      \
    if ((VMN) == 6)      asm volatile("s_waitcnt vmcnt(6)" ::: "memory");        \
    else if ((VMN) == 0) asm volatile("s_waitcnt vmcnt(0)" ::: "memory");        \
    __builtin_amdgcn_s_barrier();                                                \
    asm volatile("s_waitcnt lgkmcnt(0)" ::: "memory");                           \
    __builtin_amdgcn_s_setprio(1);                                               \
    acc[(mh)*4+0][0] = __builtin_amdgcn_mfma_f32_16x16x32_bf16(a0, bf0, acc[(mh)*4+0][0], 0, 0, 0); \
    acc[(mh)*4+0][1] = __builtin_amdgcn_mfma_f32_16x16x32_bf16(a0, bf1, acc[(mh)*4+0][1], 0, 0, 0); \
    acc[(mh)*4+0][2] = __builtin_amdgcn_mfma_f32_16x16x32_bf16(a0, bf2, acc[(mh)*4+0][2], 0, 0, 0); \
    acc[(mh)*4+0][3] = __builtin_amdgcn_mfma_f32_16x16x32_bf16(a0, bf3, acc[(mh)*4+0][3], 0, 0, 0); \
    acc[(mh)*4+1][0] = __builtin_amdgcn_mfma_f32_16x16x32_bf16(a1, bf0, acc[(mh)*4+1][0], 0, 0, 0); \
    acc[(mh)*4+1][1] = __builtin_amdgcn_mfma_f32_16x16x32_bf16(a1, bf1, acc[(mh)*4+1][1], 0, 0, 0); \
    acc[(mh)*4+1][2] = __builtin_amdgcn_mfma_f32_16x16x32_bf16(a1, bf2, acc[(mh)*4+1][2], 0, 0, 0); \
    acc[(mh)*4+1][3] = __builtin_amdgcn_mfma_f32_16x16x32_bf16(a1, bf3, acc[(mh)*4+1][3], 0, 0, 0); \
    acc[(mh)*4+2][0] = __builtin_amdgcn_mfma_f32_16x16x32_bf16(a2, bf0, acc[(mh)*4+2][0], 0, 0, 0); \
    acc[(mh)*4+2][1] = __builtin_amdgcn_mfma_f32_16x16x32_bf16(a2, bf1, acc[(mh)*4+2][1], 0, 0, 0); \
    acc[(mh)*4+2][2] = __builtin_amdgcn_mfma_f32_16x16x32_bf16(a2, bf2, acc[(mh)*4+2][2], 0, 0, 0); \
    acc[(mh)*4+2][3] = __builtin_amdgcn_mfma_f32_16x16x32_bf16(a2, bf3, acc[(mh)*4+2][3], 0, 0, 0); \
    acc[(mh)*4+3][0] = __builtin_amdgcn_mfma_f32_16x16x32_bf16(a3, bf0, acc[(mh)*4+3][0], 0, 0, 0); \
    acc[(mh)*4+3][1] = __builtin_amdgcn_mfma_f32_16x16x32_bf16(a3, bf1, acc[(mh)*4+3][1], 0, 0, 0); \
    acc[(mh)*4+3][2] = __builtin_amdgcn_mfma_f32_16x16x32_bf16(a3, bf2, acc[(mh)*4+3][2], 0, 0, 0); \
    acc[(mh)*4+3][3] = __builtin_amdgcn_mfma_f32_16x16x32_bf16(a3, bf3, acc[(mh)*4+3][3], 0, 0, 0); \
    __builtin_amdgcn_s_setprio(0);                                               \
    __builtin_amdgcn_s_barrier();                                                \
  } while (0)

__global__ __launch_bounds__(512, 2)
void conv_gemm8(const ushortT* __restrict__ wnorm, const ushortT* __restrict__ xT,
                float* __restrict__ out) {
  extern __shared__ ushortT ldsw[];
  const char* ldsc = (const char*)ldsw;

  // XCD-chunked bijective swizzle (512 blocks % 8 == 0)
  int orig = blockIdx.x;
  int wgid = (orig & 7) * 64 + (orig >> 3);
  int b  = wgid >> 5;
  int i5 = wgid & 31;
  int mp = i5 >> 4, r2 = i5 & 15;
  int nt = r2 >> 1, mt = mp * 2 + (r2 & 1);
  int co0 = mt * 256, t0 = nt * 256;

  int tid = threadIdx.x;
  int l = tid & 63, w = tid >> 6;
  int wm = w & 1, wn = w >> 1;           // 2 x 4 wave grid

  // staging constants: r0 = row (0..127) of issue q=0, jbs8 = swizzled col offset
  int r0 = tid >> 2;
  int jbs8 = (((tid & 3) ^ ((r0 >> 1) & 3)) << 3);
  // ds_read constants
  int cb = ((l >> 4) ^ ((l >> 1) & 3));
  int aoff = (wm * 128 + (l & 15)) * 64 + cb * 16;
  int boff = (wn * 64  + (l & 15)) * 64 + cb * 16;

  const ushortT* wB = wnorm + (size_t)b * COUT2 * KKTOT;
  const ushortT* xB = xT + (size_t)b * TPAD * CIN;

  f32x4 acc[8][4];
#pragma unroll
  for (int i = 0; i < 8; ++i)
#pragma unroll
    for (int j = 0; j < 4; ++j)
      acc[i][j] = (f32x4){0.f, 0.f, 0.f, 0.f};
  short8 bf0 = {}, bf1 = {}, bf2 = {}, bf3 = {};

  // prologue: kt0 all 4 halves, then kt1 {B-ks0, A-ks0, B-ks1}
  STAGE_A(0, 0, 0); STAGE_B(0, 0, 0); STAGE_A(0, 1, 0); STAGE_B(0, 1, 0);
  STAGE_B(1, 0, 1); STAGE_A(1, 0, 1); STAGE_B(1, 1, 1);
  asm volatile("s_waitcnt vmcnt(6)" ::: "memory");
  __builtin_amdgcn_s_barrier();

  for (int j = 0; j < 11; ++j) {
    int kt1 = 2 * j + 1;
    int ktn0 = 2 * j + 2, ktn1 = 2 * j + 3;
    PHASE(0, 0, 0, STAGE_A(1, 1, kt1),  -1);
    PHASE(0, 0, 1, STAGE_B(0, 0, ktn0), -1);
    PHASE(0, 1, 0, STAGE_A(0, 0, ktn0), -1);
    PHASE(0, 1, 1, STAGE_B(0, 1, ktn0),  6);
    PHASE(1, 0, 0, STAGE_A(0, 1, ktn0), -1);
    PHASE(1, 0, 1, STAGE_B(1, 0, ktn1), -1);
    PHASE(1, 1, 0, STAGE_A(1, 0, ktn1), -1);
    PHASE(1, 1, 1, STAGE_B(1, 1, ktn1),  6);
  }
  // peeled final iteration (kt0=22, kt1=23): only ph1 stages; drain at ph4
  PHASE(0, 0, 0, STAGE_A(1, 1, 23), -1);
  PHASE(0, 0, 1, {}, -1);
  PHASE(0, 1, 0, {}, -1);
  PHASE(0, 1, 1, {},  0);
  PHASE(1, 0, 0, {}, -1);
  PHASE(1, 0, 1, {}, -1);
  PHASE(1, 1, 0, {}, -1);
  PHASE(1, 1, 1, {}, -1);

  // epilogue: rows are GLU-interleaved co'; regs (x,y)/(z,w) = (a,g) channel pairs
#pragma unroll
  for (int f = 0; f < 8; ++f) {
    int cop = co0 + wm * 128 + f * 16 + ((l >> 4) << 2);
    int c = cop >> 1;
    size_t obase = ((size_t)b * (COUT2 / 2) + c) * TT;
#pragma unroll
    for (int g = 0; g < 4; ++g) {
      int t = t0 + wn * 64 + g * 16 + (l & 15);
      f32x4 v = acc[f][g];
      out[obase + t]      = v.x / (1.f + __expf(-v.y));
      out[obase + TT + t] = v.z / (1.f + __expf(-v.w));
    }
  }
}

extern "C" void kernel_launch(void* const* d_in, const int* in_sizes, int n_in,
                              void* d_out, int out_size, void* d_ws, size_t ws_size,
                              hipStream_t stream) {
  const float* x      = (const float*)d_in[0];
  const float* c_trg  = (const float*)d_in[2];
  const float* w_s    = (const float*)d_in[3];
  const float* b_s    = (const float*)d_in[4];
  const float* w_b    = (const float*)d_in[5];
  const float* b_b    = (const float*)d_in[6];
  const float* weight = (const float*)d_in[7];
  float* out = (float*)d_out;

  char* ws = (char*)d_ws;
  float*   s     = (float*)ws;                           // 32 KB
  float*   beta  = (float*)(ws + 32768);                 // 32 KB
  ushortT* xT    = (ushortT*)(ws + 65536);               // 33,587,200 B
  ushortT* wnorm = (ushortT*)(ws + 65536 + 33587200);    // 50,331,648 B

  hipFuncSetAttribute((const void*)conv_gemm8,
                      hipFuncAttributeMaxDynamicSharedMemorySize, 131072);

  style_kernel<<<32, 256, 0, stream>>>(c_trg, w_s, b_s, w_b, b_b, s, beta, xT);
  xpose_kernel<<<dim3(32, 8, 16), 256, 0, stream>>>(x, xT);
  modw_kernel<<<1024, 256, 0, stream>>>(weight, s, beta, wnorm);
  conv_gemm8<<<512, 512, 131072, stream>>>(wnorm, xT, out);
}

// Round 9
// 137.405 us; speedup vs baseline: 1.1042x; 1.0189x over previous
//
#include <hip/hip_runtime.h>
#include <math.h>

typedef __attribute__((ext_vector_type(8))) short short8;
typedef __attribute__((ext_vector_type(4))) float f32x4;
typedef unsigned short ushortT;

#define NB     16
#define CIN    512
#define TT     2048
#define COUT2  1024
#define NSTYLE 128
#define KKTOT  1536      // 3 * 512
#define TPAD   2050      // T + 2 pad rows
#define NKT    24        // K-tiles of 64

#define SCALE_LIN  0.088388347648318447f
#define SCALE_CONV 0.014731391274719736f

__device__ __forceinline__ ushortT f2bf(float f) {
  union { float f; unsigned u; } v; v.f = f;
  unsigned r = v.u + 0x7fffu + ((v.u >> 16) & 1u);
  return (ushortT)(r >> 16);
}

__device__ __forceinline__ void gload16(const void* g, void* l) {
  __builtin_amdgcn_global_load_lds(
      (const __attribute__((address_space(1))) void*)g,
      (__attribute__((address_space(3))) void*)l, 16, 0, 0);
}

// ---------------- s / beta + pad-row zeroing ----------------
__global__ void style_kernel(const float* __restrict__ c_trg,
                             const float* __restrict__ w_s, const float* __restrict__ b_s,
                             const float* __restrict__ w_b, const float* __restrict__ b_b,
                             float* __restrict__ s, float* __restrict__ beta,
                             ushortT* __restrict__ xT) {
  int gid = blockIdx.x * 256 + threadIdx.x;   // 0..8191 = b*512 + ci
  int b = gid >> 9, ci = gid & 511;
  const float* ct = c_trg + b * NSTYLE;
  const float* ws = w_s + ci * NSTYLE;
  const float* wb = w_b + ci * NSTYLE;
  float as = 0.f, ab = 0.f;
#pragma unroll 8
  for (int j = 0; j < NSTYLE; ++j) {
    float c = ct[j];
    as += c * ws[j];
    ab += c * wb[j];
  }
  s[gid]    = as * SCALE_LIN + b_s[ci];
  beta[gid] = ab * SCALE_LIN + b_b[ci];
  xT[(size_t)b * TPAD * CIN + ci] = 0;
  xT[((size_t)b * TPAD + TPAD - 1) * CIN + ci] = 0;
}

// ---------------- x [b][ci][t] f32 -> xT [b][t+1][ci] bf16 ----------------
__global__ void xpose_kernel(const float* __restrict__ x, ushortT* __restrict__ xT) {
  int b = blockIdx.z, ct = blockIdx.y, tt = blockIdx.x;
  int t0 = tt * 64, ci0 = ct * 64;
  __shared__ float tile[64][65];
  const float* xB = x + (size_t)b * CIN * TT;
  int rr = threadIdx.x >> 4;   // 0..15
  int c4 = threadIdx.x & 15;   // 0..15
#pragma unroll
  for (int it = 0; it < 4; ++it) {
    int ci = rr + it * 16;
    float4 v = *(const float4*)(xB + (size_t)(ci0 + ci) * TT + t0 + c4 * 4);
    tile[ci][c4 * 4 + 0] = v.x; tile[ci][c4 * 4 + 1] = v.y;
    tile[ci][c4 * 4 + 2] = v.z; tile[ci][c4 * 4 + 3] = v.w;
  }
  __syncthreads();
  ushortT* xTB = xT + (size_t)b * TPAD * CIN;
#pragma unroll
  for (int it = 0; it < 4; ++it) {
    int t = rr + it * 16;
    ushort4 o;
    o.x = f2bf(tile[c4 * 4 + 0][t]); o.y = f2bf(tile[c4 * 4 + 1][t]);
    o.z = f2bf(tile[c4 * 4 + 2][t]); o.w = f2bf(tile[c4 * 4 + 3][t]);
    *(ushort4*)(xTB + (size_t)(1 + t0 + t) * CIN + ci0 + c4 * 4) = o;
  }
}

// ---------------- modulate + demod-normalize weights -> bf16 ----------------
// One block per co; loops all 16 batches so weight row is read ONCE.
__global__ void modw_kernel(const float* __restrict__ weight,
                            const float* __restrict__ s, const float* __restrict__ beta,
                            ushortT* __restrict__ wnorm) {
  int co = blockIdx.x, tid = threadIdx.x;    // 256 threads, 2 ci (6 floats) each
  int ci = tid * 2;
  const float* wp = weight + (size_t)co * KKTOT + (size_t)ci * 3;
  float2 va = *(const float2*)(wp);
  float2 vb = *(const float2*)(wp + 2);
  float2 vc = *(const float2*)(wp + 4);
  float v0 = va.x, v1 = va.y, v2 = vb.x, v3 = vb.y, v4 = vc.x, v5 = vc.y;
  int r = ((co & 511) << 1) | (co >> 9);     // GLU-interleaved row
  __shared__ float rs[4], rq[4];
  for (int b = 0; b < NB; ++b) {
    float2 sv = *(const float2*)(s + b * CIN + ci);
    float2 ev = *(const float2*)(beta + b * CIN + ci);
    float w0 = SCALE_CONV * (v0 * sv.x + ev.x);
    float w1 = SCALE_CONV * (v1 * sv.x + ev.x);
    float w2 = SCALE_CONV * (v2 * sv.x + ev.x);
    float w3 = SCALE_CONV * (v3 * sv.y + ev.y);
    float w4 = SCALE_CONV * (v4 * sv.y + ev.y);
    float w5 = SCALE_CONV * (v5 * sv.y + ev.y);
    float sum = w0 + w1 + w2 + w3 + w4 + w5;
    float sq  = w0*w0 + w1*w1 + w2*w2 + w3*w3 + w4*w4 + w5*w5;
#pragma unroll
    for (int off = 32; off; off >>= 1) {
      sum += __shfl_xor(sum, off);
      sq  += __shfl_xor(sq,  off);
    }
    if ((tid & 63) == 0) { rs[tid >> 6] = sum; rq[tid >> 6] = sq; }
    __syncthreads();
    float mean  = (rs[0] + rs[1] + rs[2] + rs[3]) * (1.0f / 1536.0f);
    float demod = rsqrtf(rq[0] + rq[1] + rq[2] + rq[3] + 1e-8f);
    ushortT* dst = wnorm + ((size_t)b * COUT2 + r) * KKTOT;
    ushort2 p0, p1, p2;
    p0.x = f2bf((w0 - mean) * demod); p0.y = f2bf((w3 - mean) * demod);
    p1.x = f2bf((w1 - mean) * demod); p1.y = f2bf((w4 - mean) * demod);
    p2.x = f2bf((w2 - mean) * demod); p2.y = f2bf((w5 - mean) * demod);
    *(ushort2*)(dst +        ci) = p0;
    *(ushort2*)(dst +  512 + ci) = p1;
    *(ushort2*)(dst + 1024 + ci) = p2;
    __syncthreads();   // WAR on rs/rq before next b
  }
}

// ---------------- main conv-as-GEMM: 256^2 tile, single-barrier read-ahead ----
// Window k: {[vmcnt]; s_barrier; ds_reads for k+1 (alt reg sets); stage; MFMA k}.
// No explicit lgkm waits: compiler emits counted lgkmcnt (operands are 1 window old).
// LDS regions: ridx = ((dbuf*2 + op)*2 + ks), region [256][32] bf16 = 16384 B.
// Rows 64B = 4x16B blocks XOR-swizzled by (row>>1)&3. 8 regions = 128 KiB.

#define AFRAG(d, s, f) (*(const short8*)(ldsc + ((d) * 4 + (s)) * 16384 + aoff + (f) * 1024))
#define BFRAG(d, s, g) (*(const short8*)(ldsc + ((d) * 4 + 2 + (s)) * 16384 + boff + (g) * 1024))

#define RDA(as_, d, s, mh) do {              \
    as_##0 = AFRAG(d, s, (mh) * 4 + 0);      \
    as_##1 = AFRAG(d, s, (mh) * 4 + 1);      \
    as_##2 = AFRAG(d, s, (mh) * 4 + 2);      \
    as_##3 = AFRAG(d, s, (mh) * 4 + 3);      \
  } while (0)

#define RDB(bs_, d, s) do {                  \
    bs_##0 = BFRAG(d, s, 0);                 \
    bs_##1 = BFRAG(d, s, 1);                 \
    bs_##2 = BFRAG(d, s, 2);                 \
    bs_##3 = BFRAG(d, s, 3);                 \
  } while (0)

#define STAGE_A(d, s, kt) do {                                                   \
    int kc_ = (kt) * 64 + (s) * 32;                                              \
    gload16(wB + (size_t)(co0 + r0) * KKTOT + kc_ + jbs8,                        \
            ldsw + ((d) * 4 + (s)) * 8192 + tid * 8);                            \
    gload16(wB + (size_t)(co0 + r0 + 128) * KKTOT + kc_ + jbs8,                  \
            ldsw + ((d) * 4 + (s)) * 8192 + 4096 + tid * 8);                     \
  } while (0)

#define STAGE_B(d, s, kt) do {                                                   \
    int kc_ = (kt) * 64 + (s) * 32;                                              \
    int tap_ = kc_ >> 9; int ci_ = kc_ & 511;                                    \
    gload16(xB + (size_t)(t0 + r0 + tap_) * CIN + ci_ + jbs8,                    \
            ldsw + ((d) * 4 + 2 + (s)) * 8192 + tid * 8);                        \
    gload16(xB + (size_t)(t0 + r0 + 128 + tap_) * CIN + ci_ + jbs8,              \
            ldsw + ((d) * 4 + 2 + (s)) * 8192 + 4096 + tid * 8);                 \
  } while (0)

// VMN (pre-barrier): 6/4/0 -> s_waitcnt vmcnt(N); -1 -> none
#define PHASE(mh, au_, bu_, RD_CODE, STAGES, VMN) do {                           \
    if ((VMN) == 6)      asm volatile("s_waitcnt vmcnt(6)" ::: "memory");        \
    else if ((VMN) == 4) asm volatile("s_waitcnt vmcnt(4)" ::: "memory");        \
    else if ((VMN) == 0) asm volatile("s_waitcnt vmcnt(0)" ::: "memory");        \
    __builtin_amdgcn_s_barrier();                                                \
    RD_CODE;                                                                     \
    STAGES;                                                                      \
    __builtin_amdgcn_s_setprio(1);                                               \
    acc[(mh)*4+0][0] = __builtin_amdgcn_mfma_f32_16x16x32_bf16(au_##0, bu_##0, acc[(mh)*4+0][0], 0, 0, 0); \
    acc[(mh)*4+0][1] = __builtin_amdgcn_mfma_f32_16x16x32_bf16(au_##0, bu_##1, acc[(mh)*4+0][1], 0, 0, 0); \
    acc[(mh)*4+0][2] = __builtin_amdgcn_mfma_f32_16x16x32_bf16(au_##0, bu_##2, acc[(mh)*4+0][2], 0, 0, 0); \
    acc[(mh)*4+0][3] = __builtin_amdgcn_mfma_f32_16x16x32_bf16(au_##0, bu_##3, acc[(mh)*4+0][3], 0, 0, 0); \
    acc[(mh)*4+1][0] = __builtin_amdgcn_mfma_f32_16x16x32_bf16(au_##1, bu_##0, acc[(mh)*4+1][0], 0, 0, 0); \
    acc[(mh)*4+1][1] = __builtin_amdgcn_mfma_f32_16x16x32_bf16(au_##1, bu_##1, acc[(mh)*4+1][1], 0, 0, 0); \
    acc[(mh)*4+1][2] = __builtin_amdgcn_mfma_f32_16x16x32_bf16(au_##1, bu_##2, acc[(mh)*4+1][2], 0, 0, 0); \
    acc[(mh)*4+1][3] = __builtin_amdgcn_mfma_f32_16x16x32_bf16(au_##1, bu_##3, acc[(mh)*4+1][3], 0, 0, 0); \
    acc[(mh)*4+2][0] = __builtin_amdgcn_mfma_f32_16x16x32_bf16(au_##2, bu_##0, acc[(mh)*4+2][0], 0, 0, 0); \
    acc[(mh)*4+2][1] = __builtin_amdgcn_mfma_f32_16x16x32_bf16(au_##2, bu_##1, acc[(mh)*4+2][1], 0, 0, 0); \
    acc[(mh)*4+2][2] = __builtin_amdgcn_mfma_f32_16x16x32_bf16(au_##2, bu_##2, acc[(mh)*4+2][2], 0, 0, 0); \
    acc[(mh)*4+2][3] = __builtin_amdgcn_mfma_f32_16x16x32_bf16(au_##2, bu_##3, acc[(mh)*4+2][3], 0, 0, 0); \
    acc[(mh)*4+3][0] = __builtin_amdgcn_mfma_f32_16x16x32_bf16(au_##3, bu_##0, acc[(mh)*4+3][0], 0, 0, 0); \
    acc[(mh)*4+3][1] = __builtin_amdgcn_mfma_f32_16x16x32_bf16(au_##3, bu_##1, acc[(mh)*4+3][1], 0, 0, 0); \
    acc[(mh)*4+3][2] = __builtin_amdgcn_mfma_f32_16x16x32_bf16(au_##3, bu_##2, acc[(mh)*4+3][2], 0, 0, 0); \
    acc[(mh)*4+3][3] = __builtin_amdgcn_mfma_f32_16x16x32_bf16(au_##3, bu_##3, acc[(mh)*4+3][3], 0, 0, 0); \
    __builtin_amdgcn_s_setprio(0);                                               \
  } while (0)

__global__ __launch_bounds__(512, 2)
void conv_gemm8(const ushortT* __restrict__ wnorm, const ushortT* __restrict__ xT,
                float* __restrict__ out) {
  extern __shared__ ushortT ldsw[];
  const char* ldsc = (const char*)ldsw;

  // XCD-chunked bijective swizzle (512 blocks % 8 == 0)
  int orig = blockIdx.x;
  int wgid = (orig & 7) * 64 + (orig >> 3);
  int b  = wgid >> 5;
  int i5 = wgid & 31;
  int mp = i5 >> 4, r2 = i5 & 15;
  int nt = r2 >> 1, mt = mp * 2 + (r2 & 1);
  int co0 = mt * 256, t0 = nt * 256;

  int tid = threadIdx.x;
  int l = tid & 63, w = tid >> 6;
  int wm = w & 1, wn = w >> 1;           // 2 x 4 wave grid

  // staging constants: r0 = row (0..127) of issue q=0, jbs8 = swizzled col offset
  int r0 = tid >> 2;
  int jbs8 = (((tid & 3) ^ ((r0 >> 1) & 3)) << 3);
  // ds_read constants
  int cb = ((l >> 4) ^ ((l >> 1) & 3));
  int aoff = (wm * 128 + (l & 15)) * 64 + cb * 16;
  int boff = (wn * 64  + (l & 15)) * 64 + cb * 16;

  const ushortT* wB = wnorm + (size_t)b * COUT2 * KKTOT;
  const ushortT* xB = xT + (size_t)b * TPAD * CIN;

  f32x4 acc[8][4];
#pragma unroll
  for (int i = 0; i < 8; ++i)
#pragma unroll
    for (int j = 0; j < 4; ++j)
      acc[i][j] = (f32x4){0.f, 0.f, 0.f, 0.f};
  short8 ax0 = {}, ax1 = {}, ax2 = {}, ax3 = {};
  short8 ay0 = {}, ay1 = {}, ay2 = {}, ay3 = {};
  short8 bx0 = {}, bx1 = {}, bx2 = {}, bx3 = {};
  short8 by0 = {}, by1 = {}, by2 = {}, by3 = {};

  // prologue: kt0 all 4 halves, then kt1 {B-ks0, A-ks0, B-ks1}; then frags(win1)
  STAGE_A(0, 0, 0); STAGE_B(0, 0, 0); STAGE_A(0, 1, 0); STAGE_B(0, 1, 0);
  STAGE_B(1, 0, 1); STAGE_A(1, 0, 1); STAGE_B(1, 1, 1);
  asm volatile("s_waitcnt vmcnt(6)" ::: "memory");
  __builtin_amdgcn_s_barrier();
  RDA(ax, 0, 0, 0);
  RDB(bx, 0, 0);

  for (int j = 0; j < 11; ++j) {
    int kt1 = 2 * j + 1;
    int k0n = 2 * j + 2, k1n = 2 * j + 3;
    PHASE(0, ax, bx, { RDA(ay, 0, 0, 1); },                  STAGE_A(1, 1, kt1), -1);
    PHASE(1, ay, bx, { RDA(ax, 0, 1, 0); RDB(by, 0, 1); },   STAGE_B(0, 0, k0n), -1);
    PHASE(0, ax, by, { RDA(ay, 0, 1, 1); },                  STAGE_A(0, 0, k0n), -1);
    PHASE(1, ay, by, { RDA(ax, 1, 0, 0); RDB(bx, 1, 0); },   STAGE_B(0, 1, k0n),  4);
    PHASE(0, ax, bx, { RDA(ay, 1, 0, 1); },                  STAGE_A(0, 1, k0n), -1);
    PHASE(1, ay, bx, { RDA(ax, 1, 1, 0); RDB(by, 1, 1); },   STAGE_B(1, 0, k1n), -1);
    PHASE(0, ax, by, { RDA(ay, 1, 1, 1); },                  STAGE_A(1, 0, k1n), -1);
    PHASE(1, ay, by, { RDA(ax, 0, 0, 0); RDB(bx, 0, 0); },   STAGE_B(1, 1, k1n),  4);
  }
  // peeled final iteration (kt0=22 in dbuf0, kt1=23 in dbuf1)
  PHASE(0, ax, bx, { RDA(ay, 0, 0, 1); },                  STAGE_A(1, 1, 23), -1);
  PHASE(1, ay, bx, { RDA(ax, 0, 1, 0); RDB(by, 0, 1); },   {},                -1);
  PHASE(0, ax, by, { RDA(ay, 0, 1, 1); },                  {},                -1);
  PHASE(1, ay, by, { RDA(ax, 1, 0, 0); RDB(bx, 1, 0); },   {},                 0);
  PHASE(0, ax, bx, { RDA(ay, 1, 0, 1); },                  {},                -1);
  PHASE(1, ay, bx, { RDA(ax, 1, 1, 0); RDB(by, 1, 1); },   {},                -1);
  PHASE(0, ax, by, { RDA(ay, 1, 1, 1); },                  {},                -1);
  PHASE(1, ay, by, { },                                    {},                -1);

  // epilogue: rows are GLU-interleaved co'; regs (x,y)/(z,w) = (a,g) channel pairs
#pragma unroll
  for (int f = 0; f < 8; ++f) {
    int cop = co0 + wm * 128 + f * 16 + ((l >> 4) << 2);
    int c = cop >> 1;
    size_t obase = ((size_t)b * (COUT2 / 2) + c) * TT;
#pragma unroll
    for (int g = 0; g < 4; ++g) {
      int t = t0 + wn * 64 + g * 16 + (l & 15);
      f32x4 v = acc[f][g];
      out[obase + t]      = v.x / (1.f + __expf(-v.y));
      out[obase + TT + t] = v.z / (1.f + __expf(-v.w));
    }
  }
}

extern "C" void kernel_launch(void* const* d_in, const int* in_sizes, int n_in,
                              void* d_out, int out_size, void* d_ws, size_t ws_size,
                              hipStream_t stream) {
  const float* x      = (const float*)d_in[0];
  const float* c_trg  = (const float*)d_in[2];
  const float* w_s    = (const float*)d_in[3];
  const float* b_s    = (const float*)d_in[4];
  const float* w_b    = (const float*)d_in[5];
  const float* b_b    = (const float*)d_in[6];
  const float* weight = (const float*)d_in[7];
  float* out = (float*)d_out;

  char* ws = (char*)d_ws;
  float*   s     = (float*)ws;                           // 32 KB
  float*   beta  = (float*)(ws + 32768);                 // 32 KB
  ushortT* xT    = (ushortT*)(ws + 65536);               // 33,587,200 B
  ushortT* wnorm = (ushortT*)(ws + 65536 + 33587200);    // 50,331,648 B

  hipFuncSetAttribute((const void*)conv_gemm8,
                      hipFuncAttributeMaxDynamicSharedMemorySize, 131072);

  style_kernel<<<32, 256, 0, stream>>>(c_trg, w_s, b_s, w_b, b_b, s, beta, xT);
  xpose_kernel<<<dim3(32, 8, 16), 256, 0, stream>>>(x, xT);
  modw_kernel<<<1024, 256, 0, stream>>>(weight, s, beta, wnorm);
  conv_gemm8<<<512, 512, 131072, stream>>>(wnorm, xT, out);
}

// Round 11
// 136.320 us; speedup vs baseline: 1.1130x; 1.0080x over previous
//
#include <hip/hip_runtime.h>
#include <math.h>

typedef __attribute__((ext_vector_type(8))) short short8;
typedef __attribute__((ext_vector_type(8))) unsigned short ushort8;
typedef __attribute__((ext_vector_type(4))) float f32x4;
typedef unsigned short ushortT;

#define NB     16
#define CIN    512
#define TT     2048
#define COUT2  1024
#define NSTYLE 128
#define KKTOT  1536      // 3 * 512
#define TPAD   2050      // T + 2 pad rows
#define NKT    24        // K-tiles of 64

#define SCALE_LIN  0.088388347648318447f
#define SCALE_CONV 0.014731391274719736f

__device__ __forceinline__ ushortT f2bf(float f) {
  union { float f; unsigned u; } v; v.f = f;
  unsigned r = v.u + 0x7fffu + ((v.u >> 16) & 1u);
  return (ushortT)(r >> 16);
}

__device__ __forceinline__ void gload16(const void* g, void* l) {
  __builtin_amdgcn_global_load_lds(
      (const __attribute__((address_space(1))) void*)g,
      (__attribute__((address_space(3))) void*)l, 16, 0, 0);
}

// ---------------- s / beta + pad-row zeroing ----------------
__global__ void style_kernel(const float* __restrict__ c_trg,
                             const float* __restrict__ w_s, const float* __restrict__ b_s,
                             const float* __restrict__ w_b, const float* __restrict__ b_b,
                             float* __restrict__ s, float* __restrict__ beta,
                             ushortT* __restrict__ xT) {
  int gid = blockIdx.x * 256 + threadIdx.x;   // 0..8191 = b*512 + ci
  int b = gid >> 9, ci = gid & 511;
  const float* ct = c_trg + b * NSTYLE;
  const float* ws = w_s + ci * NSTYLE;
  const float* wb = w_b + ci * NSTYLE;
  float as = 0.f, ab = 0.f;
#pragma unroll 8
  for (int j = 0; j < NSTYLE; ++j) {
    float c = ct[j];
    as += c * ws[j];
    ab += c * wb[j];
  }
  s[gid]    = as * SCALE_LIN + b_s[ci];
  beta[gid] = ab * SCALE_LIN + b_b[ci];
  xT[(size_t)b * TPAD * CIN + ci] = 0;
  xT[((size_t)b * TPAD + TPAD - 1) * CIN + ci] = 0;
}

// ---------------- x [b][ci][t] f32 -> xT [b][t+1][ci] bf16 ----------------
__global__ void xpose_kernel(const float* __restrict__ x, ushortT* __restrict__ xT) {
  int b = blockIdx.z, ct = blockIdx.y, tt = blockIdx.x;
  int t0 = tt * 64, ci0 = ct * 64;
  __shared__ float tile[64][65];
  const float* xB = x + (size_t)b * CIN * TT;
  int rr = threadIdx.x >> 4;   // 0..15
  int c4 = threadIdx.x & 15;   // 0..15
#pragma unroll
  for (int it = 0; it < 4; ++it) {
    int ci = rr + it * 16;
    float4 v = *(const float4*)(xB + (size_t)(ci0 + ci) * TT + t0 + c4 * 4);
    tile[ci][c4 * 4 + 0] = v.x; tile[ci][c4 * 4 + 1] = v.y;
    tile[ci][c4 * 4 + 2] = v.z; tile[ci][c4 * 4 + 3] = v.w;
  }
  __syncthreads();
  ushortT* xTB = xT + (size_t)b * TPAD * CIN;
  // store phase: 16B per lane, lanes cover 64 ci contiguously per t-row group
#pragma unroll
  for (int it = 0; it < 2; ++it) {
    int idx = it * 256 + threadIdx.x;   // 0..511
    int c8 = idx & 7;                   // ci chunk (8 bf16)
    int tl = idx >> 3;                  // t within tile (0..63)
    union { ushort8 v; ushortT u[8]; } o;
#pragma unroll
    for (int j = 0; j < 8; ++j) o.u[j] = f2bf(tile[c8 * 8 + j][tl]);
    *(ushort8*)(xTB + (size_t)(1 + t0 + tl) * CIN + ci0 + c8 * 8) = o.v;
  }
}

// ---------------- modulate + demod-normalize weights -> bf16 ----------------
// One block per co; loops all 16 batches so weight row is read ONCE.
__global__ void modw_kernel(const float* __restrict__ weight,
                            const float* __restrict__ s, const float* __restrict__ beta,
                            ushortT* __restrict__ wnorm) {
  int co = blockIdx.x, tid = threadIdx.x;    // 256 threads, 2 ci (6 floats) each
  int ci = tid * 2;
  const float* wp = weight + (size_t)co * KKTOT + (size_t)ci * 3;
  float2 va = *(const float2*)(wp);
  float2 vb = *(const float2*)(wp + 2);
  float2 vc = *(const float2*)(wp + 4);
  float v0 = va.x, v1 = va.y, v2 = vb.x, v3 = vb.y, v4 = vc.x, v5 = vc.y;
  int r = ((co & 511) << 1) | (co >> 9);     // GLU-interleaved row
  __shared__ float rs[4], rq[4];
  for (int b = 0; b < NB; ++b) {
    float2 sv = *(const float2*)(s + b * CIN + ci);
    float2 ev = *(const float2*)(beta + b * CIN + ci);
    float w0 = SCALE_CONV * (v0 * sv.x + ev.x);
    float w1 = SCALE_CONV * (v1 * sv.x + ev.x);
    float w2 = SCALE_CONV * (v2 * sv.x + ev.x);
    float w3 = SCALE_CONV * (v3 * sv.y + ev.y);
    float w4 = SCALE_CONV * (v4 * sv.y + ev.y);
    float w5 = SCALE_CONV * (v5 * sv.y + ev.y);
    float sum = w0 + w1 + w2 + w3 + w4 + w5;
    float sq  = w0*w0 + w1*w1 + w2*w2 + w3*w3 + w4*w4 + w5*w5;
#pragma unroll
    for (int off = 32; off; off >>= 1) {
      sum += __shfl_xor(sum, off);
      sq  += __shfl_xor(sq,  off);
    }
    if ((tid & 63) == 0) { rs[tid >> 6] = sum; rq[tid >> 6] = sq; }
    __syncthreads();
    float mean  = (rs[0] + rs[1] + rs[2] + rs[3]) * (1.0f / 1536.0f);
    float demod = rsqrtf(rq[0] + rq[1] + rq[2] + rq[3] + 1e-8f);
    ushortT* dst = wnorm + ((size_t)b * COUT2 + r) * KKTOT;
    ushort2 p0, p1, p2;
    p0.x = f2bf((w0 - mean) * demod); p0.y = f2bf((w3 - mean) * demod);
    p1.x = f2bf((w1 - mean) * demod); p1.y = f2bf((w4 - mean) * demod);
    p2.x = f2bf((w2 - mean) * demod); p2.y = f2bf((w5 - mean) * demod);
    *(ushort2*)(dst +        ci) = p0;
    *(ushort2*)(dst +  512 + ci) = p1;
    *(ushort2*)(dst + 1024 + ci) = p2;
    __syncthreads();   // WAR on rs/rq before next b
  }
}

// ---------------- main conv-as-GEMM: 256^2 tile, 4-barrier read-ahead ----
// Barrier only before odd phases; each barrier window covers 2 phases so the
// scheduler interleaves {reads || stages || 32 MFMA}. vmcnt(6) at each odd top
// completes exactly the regions read in the following two phases. asm volatile
// "memory" on vmcnt pins memory ops to barrier sides.
// LDS regions: ridx = ((dbuf*2 + op)*2 + ks), region [256][32] bf16 = 16384 B.
// Rows 64B = 4x16B blocks XOR-swizzled by (row>>1)&3. 8 regions = 128 KiB.

#define AFRAG(d, s, f) (*(const short8*)(ldsc + ((d) * 4 + (s)) * 16384 + aoff + (f) * 1024))
#define BFRAG(d, s, g) (*(const short8*)(ldsc + ((d) * 4 + (s)) * 16384 + boff + (g) * 1024))

#define RDA(as_, d, s, mh) do {              \
    as_##0 = AFRAG(d, s, (mh) * 4 + 0);      \
    as_##1 = AFRAG(d, s, (mh) * 4 + 1);      \
    as_##2 = AFRAG(d, s, (mh) * 4 + 2);      \
    as_##3 = AFRAG(d, s, (mh) * 4 + 3);      \
  } while (0)

#define RDB(bs_, d, s) do {                  \
    bs_##0 = BFRAG(d, s, 0);                 \
    bs_##1 = BFRAG(d, s, 1);                 \
    bs_##2 = BFRAG(d, s, 2);                 \
    bs_##3 = BFRAG(d, s, 3);                 \
  } while (0)

#define STAGE_A(d, s, kt) do {                                                   \
    int kc_ = (kt) * 64 + (s) * 32;                                              \
    gload16(wB + (size_t)(co0 + r0) * KKTOT + kc_ + jbs8,                        \
            ldsw + ((d) * 4 + (s)) * 8192 + tid * 8);                            \
    gload16(wB + (size_t)(co0 + r0 + 128) * KKTOT + kc_ + jbs8,                  \
            ldsw + ((d) * 4 + (s)) * 8192 + 4096 + tid * 8);                     \
  } while (0)

#define STAGE_B(d, s, kt) do {                                                   \
    int kc_ = (kt) * 64 + (s) * 32;                                              \
    int tap_ = kc_ >> 9; int ci_ = kc_ & 511;                                    \
    gload16(xB + (size_t)(t0 + r0 + tap_) * CIN + ci_ + jbs8,                    \
            ldsw + ((d) * 4 + 2 + (s)) * 8192 + tid * 8);                        \
    gload16(xB + (size_t)(t0 + r0 + 128 + tap_) * CIN + ci_ + jbs8,              \
            ldsw + ((d) * 4 + 2 + (s)) * 8192 + 4096 + tid * 8);                 \
  } while (0)

// BAR=1: [vmcnt(VMN) if >=0; s_barrier] at top. BAR=0: no sync at top.
#define PHASE(mh, au_, bu_, RD_CODE, STAGES, VMN, BAR) do {                      \
    if (BAR) {                                                                   \
      if ((VMN) == 6)      asm volatile("s_waitcnt vmcnt(6)" ::: "memory");      \
      else if ((VMN) == 4) asm volatile("s_waitcnt vmcnt(4)" ::: "memory");      \
      else if ((VMN) == 0) asm volatile("s_waitcnt vmcnt(0)" ::: "memory");      \
      __builtin_amdgcn_s_barrier();                                              \
    }                                                                            \
    STAGES;                                                                      \
    RD_CODE;                                                                     \
    __builtin_amdgcn_s_setprio(1);                                               \
    acc[(mh)*4+0][0] = __builtin_amdgcn_mfma_f32_16x16x32_bf16(au_##0, bu_##0, acc[(mh)*4+0][0], 0, 0, 0); \
    acc[(mh)*4+0][1] = __builtin_amdgcn_mfma_f32_16x16x32_bf16(au_##0, bu_##1, acc[(mh)*4+0][1], 0, 0, 0); \
    acc[(mh)*4+0][2] = __builtin_amdgcn_mfma_f32_16x16x32_bf16(au_##0, bu_##2, acc[(mh)*4+0][2], 0, 0, 0); \
    acc[(mh)*4+0][3] = __builtin_amdgcn_mfma_f32_16x16x32_bf16(au_##0, bu_##3, acc[(mh)*4+0][3], 0, 0, 0); \
    acc[(mh)*4+1][0] = __builtin_amdgcn_mfma_f32_16x16x32_bf16(au_##1, bu_##0, acc[(mh)*4+1][0], 0, 0, 0); \
    acc[(mh)*4+1][1] = __builtin_amdgcn_mfma_f32_16x16x32_bf16(au_##1, bu_##1, acc[(mh)*4+1][1], 0, 0, 0); \
    acc[(mh)*4+1][2] = __builtin_amdgcn_mfma_f32_16x16x32_bf16(au_##1, bu_##2, acc[(mh)*4+1][2], 0, 0, 0); \
    acc[(mh)*4+1][3] = __builtin_amdgcn_mfma_f32_16x16x32_bf16(au_##1, bu_##3, acc[(mh)*4+1][3], 0, 0, 0); \
    acc[(mh)*4+2][0] = __builtin_amdgcn_mfma_f32_16x16x32_bf16(au_##2, bu_##0, acc[(mh)*4+2][0], 0, 0, 0); \
    acc[(mh)*4+2][1] = __builtin_amdgcn_mfma_f32_16x16x32_bf16(au_##2, bu_##1, acc[(mh)*4+2][1], 0, 0, 0); \
    acc[(mh)*4+2][2] = __builtin_amdgcn_mfma_f32_16x16x32_bf16(au_##2, bu_##2, acc[(mh)*4+2][2], 0, 0, 0); \
    acc[(mh)*4+2][3] = __builtin_amdgcn_mfma_f32_16x16x32_bf16(au_##2, bu_##3, acc[(mh)*4+2][3], 0, 0, 0); \
    acc[(mh)*4+3][0] = __builtin_amdgcn_mfma_f32_16x16x32_bf16(au_##3, bu_##0, acc[(mh)*4+3][0], 0, 0, 0); \
    acc[(mh)*4+3][1] = __builtin_amdgcn_mfma_f32_16x16x32_bf16(au_##3, bu_##1, acc[(mh)*4+3][1], 0, 0, 0); \
    acc[(mh)*4+3][2] = __builtin_amdgcn_mfma_f32_16x16x32_bf16(au_##3, bu_##2, acc[(mh)*4+3][2], 0, 0, 0); \
    acc[(mh)*4+3][3] = __builtin_amdgcn_mfma_f32_16x16x32_bf16(au_##3, bu_##3, acc[(mh)*4+3][3], 0, 0, 0); \
    __builtin_amdgcn_s_setprio(0);                                               \
  } while (0)

__global__ __launch_bounds__(512, 2)
void conv_gemm8(const ushortT* __restrict__ wnorm, const ushortT* __restrict__ xT,
                float* __restrict__ out) {
  extern __shared__ ushortT ldsw[];
  const char* ldsc = (const char*)ldsw;

  // XCD-chunked bijective swizzle (512 blocks % 8 == 0)
  int orig = blockIdx.x;
  int wgid = (orig & 7) * 64 + (orig >> 3);
  int b  = wgid >> 5;
  int i5 = wgid & 31;
  int mp = i5 >> 4, r2 = i5 & 15;
  int nt = r2 >> 1, mt = mp * 2 + (r2 & 1);
  int co0 = mt * 256, t0 = nt * 256;

  int tid = threadIdx.x;
  int l = tid & 63, w = tid >> 6;
  int wm = w & 1, wn = w >> 1;           // 2 x 4 wave grid

  // staging constants: r0 = row (0..127) of issue q=0, jbs8 = swizzled col offset
  int r0 = tid >> 2;
  int jbs8 = (((tid & 3) ^ ((r0 >> 1) & 3)) << 3);
  // ds_read constants
  int cb = ((l >> 4) ^ ((l >> 1) & 3));
  int aoff = (wm * 128 + (l & 15)) * 64 + cb * 16;
  int boff = 32768 + (wn * 64 + (l & 15)) * 64 + cb * 16;  // B regions at +2 ridx

  const ushortT* wB = wnorm + (size_t)b * COUT2 * KKTOT;
  const ushortT* xB = xT + (size_t)b * TPAD * CIN;

  f32x4 acc[8][4];
#pragma unroll
  for (int i = 0; i < 8; ++i)
#pragma unroll
    for (int j = 0; j < 4; ++j)
      acc[i][j] = (f32x4){0.f, 0.f, 0.f, 0.f};
  short8 ax0 = {}, ax1 = {}, ax2 = {}, ax3 = {};
  short8 ay0 = {}, ay1 = {}, ay2 = {}, ay3 = {};
  short8 bx0 = {}, bx1 = {}, bx2 = {}, bx3 = {};
  short8 by0 = {}, by1 = {}, by2 = {}, by3 = {};

  // prologue: kt0 all 4 halves, then kt1 {B-ks0, A-ks0, B-ks1}; then frags(win1)
  STAGE_A(0, 0, 0); STAGE_B(0, 0, 0); STAGE_A(0, 1, 0); STAGE_B(0, 1, 0);
  STAGE_B(1, 0, 1); STAGE_A(1, 0, 1); STAGE_B(1, 1, 1);
  asm volatile("s_waitcnt vmcnt(6)" ::: "memory");
  __builtin_amdgcn_s_barrier();
  RDA(ax, 0, 0, 0);
  RDB(bx, 0, 0);

  for (int j = 0; j < 11; ++j) {
    int kt1 = 2 * j + 1;
    int k0n = 2 * j + 2, k1n = 2 * j + 3;
    PHASE(0, ax, bx, { RDA(ay, 0, 0, 1); },                STAGE_A(1, 1, kt1),  6, 1);
    PHASE(1, ay, bx, { RDA(ax, 0, 1, 0); RDB(by, 0, 1); }, STAGE_B(0, 0, k0n), -1, 0);
    PHASE(0, ax, by, { RDA(ay, 0, 1, 1); },                STAGE_A(0, 0, k0n),  6, 1);
    PHASE(1, ay, by, { RDA(ax, 1, 0, 0); RDB(bx, 1, 0); }, STAGE_B(0, 1, k0n), -1, 0);
    PHASE(0, ax, bx, { RDA(ay, 1, 0, 1); },                STAGE_A(0, 1, k0n),  6, 1);
    PHASE(1, ay, bx, { RDA(ax, 1, 1, 0); RDB(by, 1, 1); }, STAGE_B(1, 0, k1n), -1, 0);
    PHASE(0, ax, by, { RDA(ay, 1, 1, 1); },                STAGE_A(1, 0, k1n),  6, 1);
    PHASE(1, ay, by, { RDA(ax, 0, 0, 0); RDB(bx, 0, 0); }, STAGE_B(1, 1, k1n), -1, 0);
  }
  // peeled final iteration (kt0=22 in dbuf0, kt1=23 in dbuf1)
  PHASE(0, ax, bx, { RDA(ay, 0, 0, 1); },                STAGE_A(1, 1, 23),  6, 1);
  PHASE(1, ay, bx, { RDA(ax, 0, 1, 0); RDB(by, 0, 1); }, {},                -1, 0);
  PHASE(0, ax, by, { RDA(ay, 0, 1, 1); },                {},                 4, 1);
  PHASE(1, ay, by, { RDA(ax, 1, 0, 0); RDB(bx, 1, 0); }, {},                -1, 0);
  PHASE(0, ax, bx, { RDA(ay, 1, 0, 1); },                {},                 0, 1);
  PHASE(1, ay, bx, { RDA(ax, 1, 1, 0); RDB(by, 1, 1); }, {},                -1, 0);
  PHASE(0, ax, by, { RDA(ay, 1, 1, 1); },                {},                -1, 1);
  PHASE(1, ay, by, { },                                  {},                -1, 0);

  // epilogue: rows are GLU-interleaved co'; regs (x,y)/(z,w) = (a,g) channel pairs
#pragma unroll
  for (int f = 0; f < 8; ++f) {
    int cop = co0 + wm * 128 + f * 16 + ((l >> 4) << 2);
    int c = cop >> 1;
    size_t obase = ((size_t)b * (COUT2 / 2) + c) * TT;
#pragma unroll
    for (int g = 0; g < 4; ++g) {
      int t = t0 + wn * 64 + g * 16 + (l & 15);
      f32x4 v = acc[f][g];
      out[obase + t]      = v.x / (1.f + __expf(-v.y));
      out[obase + TT + t] = v.z / (1.f + __expf(-v.w));
    }
  }
}

extern "C" void kernel_launch(void* const* d_in, const int* in_sizes, int n_in,
                              void* d_out, int out_size, void* d_ws, size_t ws_size,
                              hipStream_t stream) {
  const float* x      = (const float*)d_in[0];
  const float* c_trg  = (const float*)d_in[2];
  const float* w_s    = (const float*)d_in[3];
  const float* b_s    = (const float*)d_in[4];
  const float* w_b    = (const float*)d_in[5];
  const float* b_b    = (const float*)d_in[6];
  const float* weight = (const float*)d_in[7];
  float* out = (float*)d_out;

  char* ws = (char*)d_ws;
  float*   s     = (float*)ws;                           // 32 KB
  float*   beta  = (float*)(ws + 32768);                 // 32 KB
  ushortT* xT    = (ushortT*)(ws + 65536);               // 33,587,200 B
  ushortT* wnorm = (ushortT*)(ws + 65536 + 33587200);    // 50,331,648 B

  (void)hipFuncSetAttribute((const void*)conv_gemm8,
                            hipFuncAttributeMaxDynamicSharedMemorySize, 131072);

  style_kernel<<<32, 256, 0, stream>>>(c_trg, w_s, b_s, w_b, b_b, s, beta, xT);
  xpose_kernel<<<dim3(32, 8, 16), 256, 0, stream>>>(x, xT);
  modw_kernel<<<1024, 256, 0, stream>>>(weight, s, beta, wnorm);
  conv_gemm8<<<512, 512, 131072, stream>>>(wnorm, xT, out);
}

// Round 12
// 132.567 us; speedup vs baseline: 1.1445x; 1.0283x over previous
//
#include <hip/hip_runtime.h>
#include <math.h>

typedef __attribute__((ext_vector_type(8))) short short8;
typedef __attribute__((ext_vector_type(8))) unsigned short ushort8;
typedef __attribute__((ext_vector_type(4))) float f32x4;
typedef unsigned short ushortT;

#define NB     16
#define CIN    512
#define TT     2048
#define COUT2  1024
#define NSTYLE 128
#define KKTOT  1536      // 3 * 512
#define TPAD   2050      // T + 2 pad rows
#define NKT    24        // K-tiles of 64

#define SCALE_LIN  0.088388347648318447f
#define SCALE_CONV 0.014731391274719736f

__device__ __forceinline__ ushortT f2bf(float f) {
  union { float f; unsigned u; } v; v.f = f;
  unsigned r = v.u + 0x7fffu + ((v.u >> 16) & 1u);
  return (ushortT)(r >> 16);
}

__device__ __forceinline__ void gload16(const void* g, void* l) {
  __builtin_amdgcn_global_load_lds(
      (const __attribute__((address_space(1))) void*)g,
      (__attribute__((address_space(3))) void*)l, 16, 0, 0);
}

// ---------------- s / beta + pad-row zeroing ----------------
__global__ void style_kernel(const float* __restrict__ c_trg,
                             const float* __restrict__ w_s, const float* __restrict__ b_s,
                             const float* __restrict__ w_b, const float* __restrict__ b_b,
                             float* __restrict__ s, float* __restrict__ beta,
                             ushortT* __restrict__ xT) {
  int gid = blockIdx.x * 256 + threadIdx.x;   // 0..8191 = b*512 + ci
  int b = gid >> 9, ci = gid & 511;
  const float* ct = c_trg + b * NSTYLE;
  const float* ws = w_s + ci * NSTYLE;
  const float* wb = w_b + ci * NSTYLE;
  float as = 0.f, ab = 0.f;
#pragma unroll 8
  for (int j = 0; j < NSTYLE; ++j) {
    float c = ct[j];
    as += c * ws[j];
    ab += c * wb[j];
  }
  s[gid]    = as * SCALE_LIN + b_s[ci];
  beta[gid] = ab * SCALE_LIN + b_b[ci];
  xT[(size_t)b * TPAD * CIN + ci] = 0;
  xT[((size_t)b * TPAD + TPAD - 1) * CIN + ci] = 0;
}

// ---------------- x [b][ci][t] f32 -> xT [b][t+1][ci] bf16 ----------------
__global__ void xpose_kernel(const float* __restrict__ x, ushortT* __restrict__ xT) {
  int b = blockIdx.z, ct = blockIdx.y, tt = blockIdx.x;
  int t0 = tt * 64, ci0 = ct * 64;
  __shared__ float tile[64][65];
  const float* xB = x + (size_t)b * CIN * TT;
  int rr = threadIdx.x >> 4;   // 0..15
  int c4 = threadIdx.x & 15;   // 0..15
#pragma unroll
  for (int it = 0; it < 4; ++it) {
    int ci = rr + it * 16;
    float4 v = *(const float4*)(xB + (size_t)(ci0 + ci) * TT + t0 + c4 * 4);
    tile[ci][c4 * 4 + 0] = v.x; tile[ci][c4 * 4 + 1] = v.y;
    tile[ci][c4 * 4 + 2] = v.z; tile[ci][c4 * 4 + 3] = v.w;
  }
  __syncthreads();
  ushortT* xTB = xT + (size_t)b * TPAD * CIN;
#pragma unroll
  for (int it = 0; it < 2; ++it) {
    int idx = it * 256 + threadIdx.x;   // 0..511
    int c8 = idx & 7;                   // ci chunk (8 bf16)
    int tl = idx >> 3;                  // t within tile (0..63)
    union { ushort8 v; ushortT u[8]; } o;
#pragma unroll
    for (int j = 0; j < 8; ++j) o.u[j] = f2bf(tile[c8 * 8 + j][tl]);
    *(ushort8*)(xTB + (size_t)(1 + t0 + tl) * CIN + ci0 + c8 * 8) = o.v;
  }
}

// ---------------- modulate + demod-normalize weights -> bf16 ----------------
// Wave-per-batch: lane l owns ci in [8l, 8l+8) (24 contiguous weight floats).
// Full-wave shuffle reduction; no LDS, no barriers. Wave w handles b = 4w..4w+3.
__global__ void modw_kernel(const float* __restrict__ weight,
                            const float* __restrict__ s, const float* __restrict__ beta,
                            ushortT* __restrict__ wnorm) {
  int co = blockIdx.x;
  int wv = threadIdx.x >> 6;
  int l  = threadIdx.x & 63;
  const float* wp = weight + (size_t)co * KKTOT + l * 24;
  float v[24];
#pragma unroll
  for (int j = 0; j < 6; ++j) {
    float4 t = *(const float4*)(wp + j * 4);
    v[j * 4 + 0] = t.x; v[j * 4 + 1] = t.y; v[j * 4 + 2] = t.z; v[j * 4 + 3] = t.w;
  }
  int r = ((co & 511) << 1) | (co >> 9);     // GLU-interleaved row
#pragma unroll
  for (int bi = 0; bi < 4; ++bi) {
    int b = wv * 4 + bi;
    const float* sp = s + b * CIN + l * 8;
    const float* ep = beta + b * CIN + l * 8;
    float4 s0 = *(const float4*)(sp), s1 = *(const float4*)(sp + 4);
    float4 e0 = *(const float4*)(ep), e1 = *(const float4*)(ep + 4);
    float sv[8] = {s0.x, s0.y, s0.z, s0.w, s1.x, s1.y, s1.z, s1.w};
    float ev[8] = {e0.x, e0.y, e0.z, e0.w, e1.x, e1.y, e1.z, e1.w};
    float wm[24];
    float sum = 0.f, sq = 0.f;
#pragma unroll
    for (int c = 0; c < 8; ++c)
#pragma unroll
      for (int k = 0; k < 3; ++k) {
        float val = SCALE_CONV * (v[c * 3 + k] * sv[c] + ev[c]);
        wm[c * 3 + k] = val;
        sum += val; sq += val * val;
      }
#pragma unroll
    for (int off = 32; off; off >>= 1) {
      sum += __shfl_xor(sum, off);
      sq  += __shfl_xor(sq,  off);
    }
    float mean  = sum * (1.0f / 1536.0f);
    float demod = rsqrtf(sq + 1e-8f);
    ushortT* dst = wnorm + ((size_t)b * COUT2 + r) * KKTOT;
#pragma unroll
    for (int k = 0; k < 3; ++k) {
      union { ushort8 v8; ushortT u[8]; } o;
#pragma unroll
      for (int c = 0; c < 8; ++c) o.u[c] = f2bf((wm[c * 3 + k] - mean) * demod);
      *(ushort8*)(dst + k * 512 + l * 8) = o.v8;
    }
  }
}

// ---------------- main conv-as-GEMM: 256^2 tile, 4-barrier read-ahead ----
// R11 structure + ONE surgical sched_barrier(0) per phase between {stages+reads}
// and the MFMA cluster — prevents the scheduler from sinking the (dependence-
// free) next-phase ds_reads below the ready MFMAs, which would serialize LDS
// serve with MFMA. All waitcnt placement left to the compiler (counted lgkm).
// LDS regions: ridx = ((dbuf*2 + op)*2 + ks), region [256][32] bf16 = 16384 B.
// Rows 64B = 4x16B blocks XOR-swizzled by (row>>1)&3. 8 regions = 128 KiB.

#define AFRAG(d, s, f) (*(const short8*)(ldsc + ((d) * 4 + (s)) * 16384 + aoff + (f) * 1024))
#define BFRAG(d, s, g) (*(const short8*)(ldsc + ((d) * 4 + (s)) * 16384 + boff + (g) * 1024))

#define RDA(as_, d, s, mh) do {              \
    as_##0 = AFRAG(d, s, (mh) * 4 + 0);      \
    as_##1 = AFRAG(d, s, (mh) * 4 + 1);      \
    as_##2 = AFRAG(d, s, (mh) * 4 + 2);      \
    as_##3 = AFRAG(d, s, (mh) * 4 + 3);      \
  } while (0)

#define RDB(bs_, d, s) do {                  \
    bs_##0 = BFRAG(d, s, 0);                 \
    bs_##1 = BFRAG(d, s, 1);                 \
    bs_##2 = BFRAG(d, s, 2);                 \
    bs_##3 = BFRAG(d, s, 3);                 \
  } while (0)

#define STAGE_A(d, s, kt) do {                                                   \
    int kc_ = (kt) * 64 + (s) * 32;                                              \
    gload16(wB + (size_t)(co0 + r0) * KKTOT + kc_ + jbs8,                        \
            ldsw + ((d) * 4 + (s)) * 8192 + tid * 8);                            \
    gload16(wB + (size_t)(co0 + r0 + 128) * KKTOT + kc_ + jbs8,                  \
            ldsw + ((d) * 4 + (s)) * 8192 + 4096 + tid * 8);                     \
  } while (0)

#define STAGE_B(d, s, kt) do {                                                   \
    int kc_ = (kt) * 64 + (s) * 32;                                              \
    int tap_ = kc_ >> 9; int ci_ = kc_ & 511;                                    \
    gload16(xB + (size_t)(t0 + r0 + tap_) * CIN + ci_ + jbs8,                    \
            ldsw + ((d) * 4 + 2 + (s)) * 8192 + tid * 8);                        \
    gload16(xB + (size_t)(t0 + r0 + 128 + tap_) * CIN + ci_ + jbs8,              \
            ldsw + ((d) * 4 + 2 + (s)) * 8192 + 4096 + tid * 8);                 \
  } while (0)

// BAR=1: [vmcnt(VMN) if >=0; s_barrier] at top. BAR=0: no sync at top.
#define PHASE(mh, au_, bu_, RD_CODE, STAGES, VMN, BAR) do {                      \
    if (BAR) {                                                                   \
      if ((VMN) == 6)      asm volatile("s_waitcnt vmcnt(6)" ::: "memory");      \
      else if ((VMN) == 4) asm volatile("s_waitcnt vmcnt(4)" ::: "memory");      \
      else if ((VMN) == 0) asm volatile("s_waitcnt vmcnt(0)" ::: "memory");      \
      __builtin_amdgcn_s_barrier();                                              \
    }                                                                            \
    STAGES;                                                                      \
    RD_CODE;                                                                     \
    __builtin_amdgcn_sched_barrier(0);  /* pin reads ABOVE the MFMA cluster */   \
    __builtin_amdgcn_s_setprio(1);                                               \
    acc[(mh)*4+0][0] = __builtin_amdgcn_mfma_f32_16x16x32_bf16(au_##0, bu_##0, acc[(mh)*4+0][0], 0, 0, 0); \
    acc[(mh)*4+0][1] = __builtin_amdgcn_mfma_f32_16x16x32_bf16(au_##0, bu_##1, acc[(mh)*4+0][1], 0, 0, 0); \
    acc[(mh)*4+0][2] = __builtin_amdgcn_mfma_f32_16x16x32_bf16(au_##0, bu_##2, acc[(mh)*4+0][2], 0, 0, 0); \
    acc[(mh)*4+0][3] = __builtin_amdgcn_mfma_f32_16x16x32_bf16(au_##0, bu_##3, acc[(mh)*4+0][3], 0, 0, 0); \
    acc[(mh)*4+1][0] = __builtin_amdgcn_mfma_f32_16x16x32_bf16(au_##1, bu_##0, acc[(mh)*4+1][0], 0, 0, 0); \
    acc[(mh)*4+1][1] = __builtin_amdgcn_mfma_f32_16x16x32_bf16(au_##1, bu_##1, acc[(mh)*4+1][1], 0, 0, 0); \
    acc[(mh)*4+1][2] = __builtin_amdgcn_mfma_f32_16x16x32_bf16(au_##1, bu_##2, acc[(mh)*4+1][2], 0, 0, 0); \
    acc[(mh)*4+1][3] = __builtin_amdgcn_mfma_f32_16x16x32_bf16(au_##1, bu_##3, acc[(mh)*4+1][3], 0, 0, 0); \
    acc[(mh)*4+2][0] = __builtin_amdgcn_mfma_f32_16x16x32_bf16(au_##2, bu_##0, acc[(mh)*4+2][0], 0, 0, 0); \
    acc[(mh)*4+2][1] = __builtin_amdgcn_mfma_f32_16x16x32_bf16(au_##2, bu_##1, acc[(mh)*4+2][1], 0, 0, 0); \
    acc[(mh)*4+2][2] = __builtin_amdgcn_mfma_f32_16x16x32_bf16(au_##2, bu_##2, acc[(mh)*4+2][2], 0, 0, 0); \
    acc[(mh)*4+2][3] = __builtin_amdgcn_mfma_f32_16x16x32_bf16(au_##2, bu_##3, acc[(mh)*4+2][3], 0, 0, 0); \
    acc[(mh)*4+3][0] = __builtin_amdgcn_mfma_f32_16x16x32_bf16(au_##3, bu_##0, acc[(mh)*4+3][0], 0, 0, 0); \
    acc[(mh)*4+3][1] = __builtin_amdgcn_mfma_f32_16x16x32_bf16(au_##3, bu_##1, acc[(mh)*4+3][1], 0, 0, 0); \
    acc[(mh)*4+3][2] = __builtin_amdgcn_mfma_f32_16x16x32_bf16(au_##3, bu_##2, acc[(mh)*4+3][2], 0, 0, 0); \
    acc[(mh)*4+3][3] = __builtin_amdgcn_mfma_f32_16x16x32_bf16(au_##3, bu_##3, acc[(mh)*4+3][3], 0, 0, 0); \
    __builtin_amdgcn_s_setprio(0);                                               \
  } while (0)

__global__ __launch_bounds__(512, 2)
void conv_gemm8(const ushortT* __restrict__ wnorm, const ushortT* __restrict__ xT,
                float* __restrict__ out) {
  extern __shared__ ushortT ldsw[];
  const char* ldsc = (const char*)ldsw;

  // XCD-chunked bijective swizzle (512 blocks % 8 == 0)
  int orig = blockIdx.x;
  int wgid = (orig & 7) * 64 + (orig >> 3);
  int b  = wgid >> 5;
  int i5 = wgid & 31;
  int mp = i5 >> 4, r2 = i5 & 15;
  int nt = r2 >> 1, mt = mp * 2 + (r2 & 1);
  int co0 = mt * 256, t0 = nt * 256;

  int tid = threadIdx.x;
  int l = tid & 63, w = tid >> 6;
  int wm = w & 1, wn = w >> 1;           // 2 x 4 wave grid

  // staging constants: r0 = row (0..127) of issue q=0, jbs8 = swizzled col offset
  int r0 = tid >> 2;
  int jbs8 = (((tid & 3) ^ ((r0 >> 1) & 3)) << 3);
  // ds_read constants
  int cb = ((l >> 4) ^ ((l >> 1) & 3));
  int aoff = (wm * 128 + (l & 15)) * 64 + cb * 16;
  int boff = 32768 + (wn * 64 + (l & 15)) * 64 + cb * 16;  // B regions at +2 ridx

  const ushortT* wB = wnorm + (size_t)b * COUT2 * KKTOT;
  const ushortT* xB = xT + (size_t)b * TPAD * CIN;

  f32x4 acc[8][4];
#pragma unroll
  for (int i = 0; i < 8; ++i)
#pragma unroll
    for (int j = 0; j < 4; ++j)
      acc[i][j] = (f32x4){0.f, 0.f, 0.f, 0.f};
  short8 ax0 = {}, ax1 = {}, ax2 = {}, ax3 = {};
  short8 ay0 = {}, ay1 = {}, ay2 = {}, ay3 = {};
  short8 bx0 = {}, bx1 = {}, bx2 = {}, bx3 = {};
  short8 by0 = {}, by1 = {}, by2 = {}, by3 = {};

  // prologue: kt0 all 4 halves, then kt1 {B-ks0, A-ks0, B-ks1}; then frags(win1)
  STAGE_A(0, 0, 0); STAGE_B(0, 0, 0); STAGE_A(0, 1, 0); STAGE_B(0, 1, 0);
  STAGE_B(1, 0, 1); STAGE_A(1, 0, 1); STAGE_B(1, 1, 1);
  asm volatile("s_waitcnt vmcnt(6)" ::: "memory");
  __builtin_amdgcn_s_barrier();
  RDA(ax, 0, 0, 0);
  RDB(bx, 0, 0);

  for (int j = 0; j < 11; ++j) {
    int kt1 = 2 * j + 1;
    int k0n = 2 * j + 2, k1n = 2 * j + 3;
    PHASE(0, ax, bx, { RDA(ay, 0, 0, 1); },                STAGE_A(1, 1, kt1),  6, 1);
    PHASE(1, ay, bx, { RDA(ax, 0, 1, 0); RDB(by, 0, 1); }, STAGE_B(0, 0, k0n), -1, 0);
    PHASE(0, ax, by, { RDA(ay, 0, 1, 1); },                STAGE_A(0, 0, k0n),  6, 1);
    PHASE(1, ay, by, { RDA(ax, 1, 0, 0); RDB(bx, 1, 0); }, STAGE_B(0, 1, k0n), -1, 0);
    PHASE(0, ax, bx, { RDA(ay, 1, 0, 1); },                STAGE_A(0, 1, k0n),  6, 1);
    PHASE(1, ay, bx, { RDA(ax, 1, 1, 0); RDB(by, 1, 1); }, STAGE_B(1, 0, k1n), -1, 0);
    PHASE(0, ax, by, { RDA(ay, 1, 1, 1); },                STAGE_A(1, 0, k1n),  6, 1);
    PHASE(1, ay, by, { RDA(ax, 0, 0, 0); RDB(bx, 0, 0); }, STAGE_B(1, 1, k1n), -1, 0);
  }
  // peeled final iteration (kt0=22 in dbuf0, kt1=23 in dbuf1)
  PHASE(0, ax, bx, { RDA(ay, 0, 0, 1); },                STAGE_A(1, 1, 23),  6, 1);
  PHASE(1, ay, bx, { RDA(ax, 0, 1, 0); RDB(by, 0, 1); }, {},                -1, 0);
  PHASE(0, ax, by, { RDA(ay, 0, 1, 1); },                {},                 4, 1);
  PHASE(1, ay, by, { RDA(ax, 1, 0, 0); RDB(bx, 1, 0); }, {},                -1, 0);
  PHASE(0, ax, bx, { RDA(ay, 1, 0, 1); },                {},                 0, 1);
  PHASE(1, ay, bx, { RDA(ax, 1, 1, 0); RDB(by, 1, 1); }, {},                -1, 0);
  PHASE(0, ax, by, { RDA(ay, 1, 1, 1); },                {},                -1, 1);
  PHASE(1, ay, by, { },                                  {},                -1, 0);

  // epilogue: rows are GLU-interleaved co'; regs (x,y)/(z,w) = (a,g) channel pairs
#pragma unroll
  for (int f = 0; f < 8; ++f) {
    int cop = co0 + wm * 128 + f * 16 + ((l >> 4) << 2);
    int c = cop >> 1;
    size_t obase = ((size_t)b * (COUT2 / 2) + c) * TT;
#pragma unroll
    for (int g = 0; g < 4; ++g) {
      int t = t0 + wn * 64 + g * 16 + (l & 15);
      f32x4 v = acc[f][g];
      out[obase + t]      = v.x / (1.f + __expf(-v.y));
      out[obase + TT + t] = v.z / (1.f + __expf(-v.w));
    }
  }
}

extern "C" void kernel_launch(void* const* d_in, const int* in_sizes, int n_in,
                              void* d_out, int out_size, void* d_ws, size_t ws_size,
                              hipStream_t stream) {
  const float* x      = (const float*)d_in[0];
  const float* c_trg  = (const float*)d_in[2];
  const float* w_s    = (const float*)d_in[3];
  const float* b_s    = (const float*)d_in[4];
  const float* w_b    = (const float*)d_in[5];
  const float* b_b    = (const float*)d_in[6];
  const float* weight = (const float*)d_in[7];
  float* out = (float*)d_out;

  char* ws = (char*)d_ws;
  float*   s     = (float*)ws;                           // 32 KB
  float*   beta  = (float*)(ws + 32768);                 // 32 KB
  ushortT* xT    = (ushortT*)(ws + 65536);               // 33,587,200 B
  ushortT* wnorm = (ushortT*)(ws + 65536 + 33587200);    // 50,331,648 B

  (void)hipFuncSetAttribute((const void*)conv_gemm8,
                            hipFuncAttributeMaxDynamicSharedMemorySize, 131072);

  style_kernel<<<32, 256, 0, stream>>>(c_trg, w_s, b_s, w_b, b_b, s, beta, xT);
  xpose_kernel<<<dim3(32, 8, 16), 256, 0, stream>>>(x, xT);
  modw_kernel<<<1024, 256, 0, stream>>>(weight, s, beta, wnorm);
  conv_gemm8<<<512, 512, 131072, stream>>>(wnorm, xT, out);
}